// Round 1
// 463.636 us; speedup vs baseline: 1.0224x; 1.0224x over previous
//
#include <hip/hip_runtime.h>
#include <hip/hip_bf16.h>
#include <math.h>

static constexpr int BN   = 16384;
static constexpr int NFFT = 512;
static constexpr int NBIN = 257;
static constexpr int NH   = 128;
static constexpr int NE   = 256;
static constexpr int NG   = 512;
static constexpr float EPSF  = 1.1920929e-07f;
static constexpr float LNEPS = 1e-07f;

using short8  = __attribute__((ext_vector_type(8))) short;
using float4v = __attribute__((ext_vector_type(4))) float;

__device__ __forceinline__ float sigm(float x){ return 1.0f/(1.0f+expf(-x)); }
__device__ __forceinline__ ushort f2b(float v){
  __hip_bfloat16 b = __float2bfloat16(v);
  return *reinterpret_cast<ushort*>(&b);
}
__device__ __forceinline__ float b2f(ushort u){
  __hip_bfloat16 b = *reinterpret_cast<__hip_bfloat16*>(&u);
  return __bfloat162float(b);
}
__device__ __forceinline__ void split(float v, ushort* hi, ushort* lo){
  ushort h = f2b(v);
  *hi = h;
  *lo = f2b(v - b2f(h));
}

// async global -> LDS, 16B per lane. LDS dest must be wave-uniform base;
// HW writes base + lane*16. Global src is per-lane.
__device__ __forceinline__ void gload16(const ushort* g, ushort* l){
  __builtin_amdgcn_global_load_lds(
      (const __attribute__((address_space(1))) unsigned int*)g,
      (__attribute__((address_space(3))) unsigned int*)l,
      16, 0, 0);
}

// ================= MFMA bf16x2 NT GEMM =================
// C[row][col] = sum_k A[row][k]*B[col][k] (+ optional phase2 A2/B2) + bias
// A planes: [16384][lda] bf16 hi/lo. B planes: [Mp][K] (ld == K). All dims padded:
// K mult of 32, Mp mult of 128. C: f32 (ldc) or hi/lo bf16 planes.
//
// LDS tile: [128 rows][64 ushorts] = 128 B/row, 8 x 16B slots/row.
// Logical slot s: s<4 -> hi plane k-chunk s (8 elems), s>=4 -> lo chunk s-4.
// Physical slot p at row r holds logical slot p ^ (r&7)  (XOR swizzle).
// global_load_lds writes LINEAR dest; the swizzle is folded into the
// per-lane global source address (inverse == same involution). Reads XOR
// the byte offset with (r&7)<<4 -> 2-way bank aliasing (free, m136).
__global__ __launch_bounds__(256)
void mfma_gemm(const ushort* __restrict__ Ahi, const ushort* __restrict__ Alo,
               int lda, int K,
               const ushort* __restrict__ Bhi, const ushort* __restrict__ Blo,
               const ushort* __restrict__ A2hi, const ushort* __restrict__ A2lo,
               int lda2, int K2,
               const ushort* __restrict__ B2hi, const ushort* __restrict__ B2lo,
               const float* __restrict__ bias,
               float* __restrict__ C, ushort* __restrict__ Chi,
               ushort* __restrict__ Clo, int ldc)
{
  __shared__ ushort As[128][64];
  __shared__ ushort Bs[128][64];
  const int tid  = threadIdx.x;
  const int row0 = blockIdx.x * 128;
  const int col0 = blockIdx.y * 128;
  const int lane = tid & 63;
  const int wv   = tid >> 6;
  const int wr   = (wv >> 1) * 64;   // wave row offset in tile
  const int wc   = (wv & 1) * 64;    // wave col offset in tile
  const int fr   = lane & 15;
  const int quad = lane >> 4;

  // staging geometry: wave wv covers segments g=4wv..4wv+3 of each matrix,
  // segment g = rows g*8..g*8+7 (1 KB). Lane -> (row-in-seg, physical slot).
  const int lrow   = lane >> 3;        // 0..7
  const int pslot  = lane & 7;
  const int lslot  = pslot ^ lrow;     // logical slot this lane must fetch
  const int kchunk = (lslot & 3) * 8;  // element offset within 32-elem k-tile
  const bool isHi  = (lslot < 4);

  float4v acc[4][4];
  #pragma unroll
  for (int i = 0; i < 4; ++i)
    #pragma unroll
    for (int j = 0; j < 4; ++j)
      acc[i][j] = float4v{0.f, 0.f, 0.f, 0.f};

  const char* Ab = (const char*)&As[0][0];
  const char* Bb = (const char*)&Bs[0][0];

  #pragma unroll 1
  for (int phase = 0; phase < 2; ++phase) {
    const ushort* pAhi = phase ? A2hi : Ahi;
    const ushort* pAlo = phase ? A2lo : Alo;
    const ushort* pBhi = phase ? B2hi : Bhi;
    const ushort* pBlo = phase ? B2lo : Blo;
    const int ld_a = phase ? lda2 : lda;
    const int KK   = phase ? K2 : K;
    if (!pAhi) continue;

    const ushort* aplane = isHi ? pAhi : pAlo;
    const ushort* bplane = isHi ? pBhi : pBlo;
    size_t aoff[4], boff[4];
    #pragma unroll
    for (int si = 0; si < 4; ++si) {
      const int r = (wv * 4 + si) * 8 + lrow;
      aoff[si] = (size_t)(row0 + r) * ld_a + kchunk;
      boff[si] = (size_t)(col0 + r) * KK   + kchunk;
    }

    for (int kt = 0; kt < KK / 32; ++kt) {
      // ---- stage: 8 x global_load_lds(16B) per wave ----
      #pragma unroll
      for (int si = 0; si < 4; ++si) {
        gload16(aplane + aoff[si] + kt * 32, &As[(wv * 4 + si) * 8][0]);
        gload16(bplane + boff[si] + kt * 32, &Bs[(wv * 4 + si) * 8][0]);
      }
      asm volatile("s_waitcnt vmcnt(0)" ::: "memory");
      __syncthreads();

      // ---- fragments (swizzled reads) ----
      short8 ah[4], al[4], bh[4], bl[4];
      #pragma unroll
      for (int i = 0; i < 4; ++i) {
        const int ra  = wr + i * 16 + fr;
        const int rb  = wc + i * 16 + fr;
        const int swa = (ra & 7) << 4;
        const int swb = (rb & 7) << 4;
        ah[i] = *(const short8*)(Ab + ra * 128 + ((quad << 4) ^ swa));
        al[i] = *(const short8*)(Ab + ra * 128 + ((64 | (quad << 4)) ^ swa));
        bh[i] = *(const short8*)(Bb + rb * 128 + ((quad << 4) ^ swb));
        bl[i] = *(const short8*)(Bb + rb * 128 + ((64 | (quad << 4)) ^ swb));
      }
      #pragma unroll
      for (int i = 0; i < 4; ++i)
        #pragma unroll
        for (int j = 0; j < 4; ++j) {
          acc[i][j] = __builtin_amdgcn_mfma_f32_16x16x32_bf16(ah[i], bh[j], acc[i][j], 0, 0, 0);
          acc[i][j] = __builtin_amdgcn_mfma_f32_16x16x32_bf16(ah[i], bl[j], acc[i][j], 0, 0, 0);
          acc[i][j] = __builtin_amdgcn_mfma_f32_16x16x32_bf16(al[i], bh[j], acc[i][j], 0, 0, 0);
        }
      __syncthreads();
    }
  }

  // ---- epilogue: C/D layout col=lane&15, row=quad*4+reg ----
  #pragma unroll
  for (int j = 0; j < 4; ++j) {
    const int colb = col0 + wc + j * 16 + fr;
    const float bv = bias ? bias[colb] : 0.f;
    #pragma unroll
    for (int i = 0; i < 4; ++i) {
      #pragma unroll
      for (int r = 0; r < 4; ++r) {
        const int row = row0 + wr + i * 16 + quad * 4 + r;
        const float v = acc[i][j][r] + bv;
        const size_t idx = (size_t)row * ldc + colb;
        if (C) C[idx] = v;
        else   split(v, &Chi[idx], &Clo[idx]);
      }
    }
  }
}

// ================= weight / bias prep =================
__global__ void wconv(const float* __restrict__ src, int M0, int K0,
                      ushort* __restrict__ hi, ushort* __restrict__ lo,
                      int Mp, int Kp){
  int idx = blockIdx.x * blockDim.x + threadIdx.x;
  if (idx >= Mp * Kp) return;
  int r = idx / Kp, c = idx - r * Kp;
  float v = (r < M0 && c < K0) ? src[(size_t)r * K0 + c] : 0.f;
  split(v, &hi[idx], &lo[idx]);
}

__global__ void bias_pad(const float* __restrict__ s1, const float* __restrict__ s2,
                         int L, float* __restrict__ dst, int Lp){
  int idx = blockIdx.x * blockDim.x + threadIdx.x;
  if (idx >= Lp) return;
  float v = 0.f;
  if (idx < L) { v = s1[idx]; if (s2) v += s2[idx]; }
  dst[idx] = v;
}

// fwdT planes [512 cols][512 n]: col c=2k -> cos(2pi k n/512), c=2k+1 -> -sin. k=0..255.
__global__ void fill_fwd(ushort* __restrict__ hi, ushort* __restrict__ lo){
  int idx = blockIdx.x * blockDim.x + threadIdx.x;
  if (idx >= 512 * 512) return;
  int c = idx >> 9, n = idx & 511;
  int k = c >> 1, m = (k * n) & 511;
  float th = (float)m * (6.283185307179586f / 512.0f);
  float s, co; sincosf(th, &s, &co);
  float v = (c & 1) ? -s : co;
  split(v, &hi[idx], &lo[idx]);
}

// invT planes [512 n][544 c]: c=2k -> w_k cos, c=2k+1 -> -w_k sin (k<256);
// c=512 -> Nyquist (+/-1)/512; c=513..543 -> 0
__global__ void fill_inv(ushort* __restrict__ hi, ushort* __restrict__ lo){
  int idx = blockIdx.x * blockDim.x + threadIdx.x;
  if (idx >= 512 * 544) return;
  int n = idx / 544, c = idx - n * 544;
  float v = 0.f;
  if (c < 512) {
    int k = c >> 1, m = (k * n) & 511;
    float th = (float)m * (6.283185307179586f / 512.0f);
    float s, co; sincosf(th, &s, &co);
    float w = (k == 0) ? (1.0f / 512.0f) : (2.0f / 512.0f);
    v = (c & 1) ? -w * s : w * co;
  } else if (c == 512) {
    v = ((n & 1) ? -1.0f : 1.0f) / 512.0f;
  }
  split(v, &hi[idx], &lo[idx]);
}

// ================= elementwise =================
// x f32 [16384][512] -> hi/lo planes [16384][544] (cols 512.. zero)
__global__ void convert_x(const float* __restrict__ x,
                          ushort* __restrict__ hi, ushort* __restrict__ lo){
  int idx = blockIdx.x * blockDim.x + threadIdx.x;
  if (idx >= BN * 544) return;
  int r = idx / 544, c = idx - r * 544;
  float v = (c < 512) ? x[(size_t)r * 512 + c] : 0.f;
  split(v, &hi[idx], &lo[idx]);
}

// Nyquist bin: RI[n][512] = sum x[n][i]*(-1)^i ; RI[n][513] = 0
__global__ void nyq_kernel(const float* __restrict__ x, float* __restrict__ RI){
  int row  = blockIdx.x * 4 + (threadIdx.x >> 6);
  int lane = threadIdx.x & 63;
  const float* xr = x + (size_t)row * 512;
  float s = 0.f;
  #pragma unroll
  for (int i = 0; i < 8; ++i) {
    int n = lane + 64 * i;
    float v = xr[n];
    s += (n & 1) ? -v : v;
  }
  #pragma unroll
  for (int off = 32; off >= 1; off >>= 1) s += __shfl_xor(s, off, 64);
  if (lane == 0) {
    RI[(size_t)row * 514 + 512] = s;
    RI[(size_t)row * 514 + 513] = 0.f;
  }
}

// mag planes [16384][288] from RI f32 [16384][514]
__global__ void magphase_kernel(const float* __restrict__ RI,
                                ushort* __restrict__ mhi, ushort* __restrict__ mlo){
  int idx = blockIdx.x * blockDim.x + threadIdx.x;
  if (idx >= BN * 288) return;
  int n = idx / 288, j = idx - n * 288;
  float mag = 0.f;
  if (j < NBIN) {
    float r  = RI[(size_t)n * 514 + 2 * j];
    float im = RI[(size_t)n * 514 + 2 * j + 1];
    mag = sqrtf(fmaxf(r * r + im * im, EPSF));
  }
  split(mag, &mhi[idx], &mlo[idx]);
}

// in_state (2,BN,NH,2) f32 -> H hi/lo planes + C f32 (both layers)
__global__ void unpack_state(const float* __restrict__ st,
                             ushort* __restrict__ h1hi, ushort* __restrict__ h1lo,
                             float* __restrict__ c1,
                             ushort* __restrict__ h2hi, ushort* __restrict__ h2lo,
                             float* __restrict__ c2){
  int idx = blockIdx.x * blockDim.x + threadIdx.x;
  if (idx >= BN * NH) return;
  split(st[(size_t)idx * 2], &h1hi[idx], &h1lo[idx]);
  c1[idx] = st[(size_t)idx * 2 + 1];
  size_t off = (size_t)BN * NH * 2;
  split(st[off + (size_t)idx * 2], &h2hi[idx], &h2lo[idx]);
  c2[idx] = st[off + (size_t)idx * 2 + 1];
}

// gates G[n][512] + c -> h (hi/lo planes), c (f32), out_state f32 (h,c interleaved)
__global__ void lstm_cell(const float* __restrict__ G,
                          float* __restrict__ c,
                          ushort* __restrict__ hhi, ushort* __restrict__ hlo,
                          float* __restrict__ ost){
  int idx = blockIdx.x * blockDim.x + threadIdx.x;
  if (idx >= BN * NH) return;
  int n = idx >> 7, j = idx & 127;
  const float* g = G + (size_t)n * NG;
  float gi = g[j], gf = g[NH + j], gc = g[2 * NH + j], go = g[3 * NH + j];
  float cp = c[idx];
  float cn = sigm(gf) * cp + sigm(gi) * tanhf(gc);
  float hn = sigm(go) * tanhf(cn);
  c[idx] = cn;
  split(hn, &hhi[idx], &hlo[idx]);
  ost[(size_t)idx * 2]     = hn;
  ost[(size_t)idx * 2 + 1] = cn;
}

// est stft -> S hi/lo planes [16384][544] (pairs; j>=257 zero)
__global__ void est_build(const float* __restrict__ Mpre, int ldm,
                          const ushort* __restrict__ mhi, const ushort* __restrict__ mlo,
                          const float* __restrict__ RI,
                          ushort* __restrict__ shi, ushort* __restrict__ slo){
  int idx = blockIdx.x * blockDim.x + threadIdx.x;
  if (idx >= BN * 272) return;
  int n = idx / 272, j = idx - n * 272;
  float cr = 0.f, ci = 0.f;
  if (j < NBIN) {
    float m   = sigm(Mpre[(size_t)n * ldm + j]);
    float mag = b2f(mhi[(size_t)n * 288 + j]) + b2f(mlo[(size_t)n * 288 + j]);
    float e   = m * mag;
    float r   = RI[(size_t)n * 514 + 2 * j];
    float im  = RI[(size_t)n * 514 + 2 * j + 1];
    float re = r + EPSF, ie = im + EPSF;
    float hyp = fmaxf(sqrtf(re * re + ie * ie), 1e-35f);
    cr = e * re / hyp;
    ci = e * ie / hyp;
  }
  size_t p = (size_t)n * 544 + 2 * j;
  split(cr, &shi[p], &slo[p]);
  split(ci, &shi[p + 1], &slo[p + 1]);
}

// LayerNorm over 256 -> ENCN hi/lo planes
__global__ void ln_kernel(const float* __restrict__ ENC,
                          const float* __restrict__ gamma,
                          const float* __restrict__ beta,
                          ushort* __restrict__ ohi, ushort* __restrict__ olo){
  int row = blockIdx.x;
  int t = threadIdx.x;   // 64
  const float* e = ENC + (size_t)row * NE;
  float v[4]; float s = 0.f;
  #pragma unroll
  for (int i = 0; i < 4; ++i) { v[i] = e[t + 64 * i]; s += v[i]; }
  #pragma unroll
  for (int off = 32; off >= 1; off >>= 1) s += __shfl_xor(s, off, 64);
  float mean = s * (1.0f / NE);
  float d[4]; float ss = 0.f;
  #pragma unroll
  for (int i = 0; i < 4; ++i) { d[i] = v[i] - mean; ss += d[i] * d[i]; }
  #pragma unroll
  for (int off = 32; off >= 1; off >>= 1) ss += __shfl_xor(ss, off, 64);
  float inv = 1.0f / sqrtf(ss * (1.0f / NE) + LNEPS);
  #pragma unroll
  for (int i = 0; i < 4; ++i) {
    int col = t + 64 * i;
    float o = d[i] * inv * gamma[col] + beta[col];
    size_t p = (size_t)row * NE + col;
    split(o, &ohi[p], &olo[p]);
  }
}

// D = sigmoid(mask2pre) * ENC -> hi/lo planes
__global__ void dec_in(const float* __restrict__ Mpre,
                       const float* __restrict__ ENC,
                       ushort* __restrict__ dhi, ushort* __restrict__ dlo){
  int idx = blockIdx.x * blockDim.x + threadIdx.x;
  if (idx >= BN * NE) return;
  int n = idx >> 8, j = idx & 255;
  float v = sigm(Mpre[(size_t)n * 512 + j]) * ENC[idx];
  split(v, &dhi[idx], &dlo[idx]);
}

// ================= launch =================
extern "C" void kernel_launch(void* const* d_in, const int* in_sizes, int n_in,
                              void* d_out, int out_size, void* d_ws, size_t ws_size,
                              hipStream_t stream)
{
  const float* x       = (const float*)d_in[0];
  const float* st1     = (const float*)d_in[1];
  const float* st2     = (const float*)d_in[2];
  const float* s1_wih1 = (const float*)d_in[3];
  const float* s1_whh1 = (const float*)d_in[4];
  const float* s1_bih1 = (const float*)d_in[5];
  const float* s1_bhh1 = (const float*)d_in[6];
  const float* s1_wih2 = (const float*)d_in[7];
  const float* s1_whh2 = (const float*)d_in[8];
  const float* s1_bih2 = (const float*)d_in[9];
  const float* s1_bhh2 = (const float*)d_in[10];
  const float* s1_dw   = (const float*)d_in[11];
  const float* s1_db   = (const float*)d_in[12];
  const float* enc_w   = (const float*)d_in[13];
  const float* ln_g    = (const float*)d_in[14];
  const float* ln_b    = (const float*)d_in[15];
  const float* s2_wih1 = (const float*)d_in[16];
  const float* s2_whh1 = (const float*)d_in[17];
  const float* s2_bih1 = (const float*)d_in[18];
  const float* s2_bhh1 = (const float*)d_in[19];
  const float* s2_wih2 = (const float*)d_in[20];
  const float* s2_whh2 = (const float*)d_in[21];
  const float* s2_bih2 = (const float*)d_in[22];
  const float* s2_bhh2 = (const float*)d_in[23];
  const float* s2_dw   = (const float*)d_in[24];
  const float* s2_db   = (const float*)d_in[25];
  const float* dec_w   = (const float*)d_in[26];

  float* out_dec = (float*)d_out;
  float* out_st1 = out_dec + (size_t)BN * NFFT;
  float* out_st2 = out_st1 + (size_t)2 * BN * NH * 2;

  // ---- workspace (byte bump allocator, 256B aligned) ----
  char* base = (char*)d_ws;
  size_t off = 0;
  auto alloc = [&](size_t bytes) -> void* {
    off = (off + 255) & ~(size_t)255;
    void* p = base + off;
    off += bytes;
    return p;
  };
  ushort* fwdThi = (ushort*)alloc((size_t)512 * 512 * 2);
  ushort* fwdTlo = (ushort*)alloc((size_t)512 * 512 * 2);
  ushort* invThi = (ushort*)alloc((size_t)512 * 544 * 2);
  ushort* invTlo = (ushort*)alloc((size_t)512 * 544 * 2);
  ushort* XShi   = (ushort*)alloc((size_t)BN * 544 * 2);  // x planes, later est-stft planes
  ushort* XSlo   = (ushort*)alloc((size_t)BN * 544 * 2);
  float*  RI     = (float*) alloc((size_t)BN * 514 * 4);
  float*  G      = (float*) alloc((size_t)BN * 512 * 4);  // gates / mask-pre; later Y1 planes
  char*   R1     = (char*)  alloc((size_t)BN * NE * 4 * 2); // MAG planes, later ENC + ENCN
  ushort* h1hi   = (ushort*)alloc((size_t)BN * NH * 2);
  ushort* h1lo   = (ushort*)alloc((size_t)BN * NH * 2);
  ushort* h2hi   = (ushort*)alloc((size_t)BN * NH * 2);
  ushort* h2lo   = (ushort*)alloc((size_t)BN * NH * 2);
  float*  C1     = (float*) alloc((size_t)BN * NH * 4);
  float*  C2     = (float*) alloc((size_t)BN * NH * 4);
  // weight planes
  ushort* w11hi = (ushort*)alloc((size_t)512*288*2); ushort* w11lo = (ushort*)alloc((size_t)512*288*2);
  ushort* wh1hi = (ushort*)alloc((size_t)512*128*2); ushort* wh1lo = (ushort*)alloc((size_t)512*128*2);
  ushort* w12hi = (ushort*)alloc((size_t)512*128*2); ushort* w12lo = (ushort*)alloc((size_t)512*128*2);
  ushort* wh2hi = (ushort*)alloc((size_t)512*128*2); ushort* wh2lo = (ushort*)alloc((size_t)512*128*2);
  ushort* dw1hi = (ushort*)alloc((size_t)384*128*2); ushort* dw1lo = (ushort*)alloc((size_t)384*128*2);
  ushort* encwhi= (ushort*)alloc((size_t)256*512*2); ushort* encwlo= (ushort*)alloc((size_t)256*512*2);
  ushort* w21hi = (ushort*)alloc((size_t)512*256*2); ushort* w21lo = (ushort*)alloc((size_t)512*256*2);
  ushort* wh3hi = (ushort*)alloc((size_t)512*128*2); ushort* wh3lo = (ushort*)alloc((size_t)512*128*2);
  ushort* w22hi = (ushort*)alloc((size_t)512*128*2); ushort* w22lo = (ushort*)alloc((size_t)512*128*2);
  ushort* wh4hi = (ushort*)alloc((size_t)512*128*2); ushort* wh4lo = (ushort*)alloc((size_t)512*128*2);
  ushort* dw2hi = (ushort*)alloc((size_t)256*128*2); ushort* dw2lo = (ushort*)alloc((size_t)256*128*2);
  ushort* decwhi= (ushort*)alloc((size_t)512*256*2); ushort* decwlo= (ushort*)alloc((size_t)512*256*2);
  float* bg1 = (float*)alloc(512*4); float* bg2 = (float*)alloc(512*4);
  float* bm1 = (float*)alloc(384*4);
  float* bg3 = (float*)alloc(512*4); float* bg4 = (float*)alloc(512*4);
  float* bm2 = (float*)alloc(256*4);
  (void)ws_size; (void)in_sizes; (void)n_in; (void)out_size;

  // region overlays
  ushort* maghi  = (ushort*)R1;                              // [BN][288]
  ushort* maglo  = (ushort*)(R1 + (size_t)BN * 288 * 2);
  float*  ENC    = (float*)R1;                               // [BN][256] (MAG dead)
  ushort* ENCNhi = (ushort*)(R1 + (size_t)BN * NE * 4);      // [BN][256]
  ushort* ENCNlo = (ushort*)(R1 + (size_t)BN * NE * 4 + (size_t)BN * NE * 2);
  ushort* Dhi    = ENCNhi;                                   // dec-in planes (ENCN dead)
  ushort* Dlo    = ENCNlo;
  ushort* Y1hi   = (ushort*)G;                               // [BN][512] (gates dead)
  ushort* Y1lo   = (ushort*)G + (size_t)BN * 512;

  const dim3 blk(256);
  auto ceilb = [](long n){ return (int)((n + 255) / 256); };

  // ---- prep: twiddles, weights, biases ----
  fill_fwd<<<ceilb((long)512*512), blk, 0, stream>>>(fwdThi, fwdTlo);
  fill_inv<<<ceilb((long)512*544), blk, 0, stream>>>(invThi, invTlo);
  wconv<<<ceilb((long)512*288), blk, 0, stream>>>(s1_wih1, 512, 257, w11hi, w11lo, 512, 288);
  wconv<<<ceilb((long)512*128), blk, 0, stream>>>(s1_whh1, 512, 128, wh1hi, wh1lo, 512, 128);
  wconv<<<ceilb((long)512*128), blk, 0, stream>>>(s1_wih2, 512, 128, w12hi, w12lo, 512, 128);
  wconv<<<ceilb((long)512*128), blk, 0, stream>>>(s1_whh2, 512, 128, wh2hi, wh2lo, 512, 128);
  wconv<<<ceilb((long)384*128), blk, 0, stream>>>(s1_dw,   257, 128, dw1hi, dw1lo, 384, 128);
  wconv<<<ceilb((long)256*512), blk, 0, stream>>>(enc_w,   256, 512, encwhi, encwlo, 256, 512);
  wconv<<<ceilb((long)512*256), blk, 0, stream>>>(s2_wih1, 512, 256, w21hi, w21lo, 512, 256);
  wconv<<<ceilb((long)512*128), blk, 0, stream>>>(s2_whh1, 512, 128, wh3hi, wh3lo, 512, 128);
  wconv<<<ceilb((long)512*128), blk, 0, stream>>>(s2_wih2, 512, 128, w22hi, w22lo, 512, 128);
  wconv<<<ceilb((long)512*128), blk, 0, stream>>>(s2_whh2, 512, 128, wh4hi, wh4lo, 512, 128);
  wconv<<<ceilb((long)256*128), blk, 0, stream>>>(s2_dw,   256, 128, dw2hi, dw2lo, 256, 128);
  wconv<<<ceilb((long)512*256), blk, 0, stream>>>(dec_w,   512, 256, decwhi, decwlo, 512, 256);
  bias_pad<<<2, blk, 0, stream>>>(s1_bih1, s1_bhh1, 512, bg1, 512);
  bias_pad<<<2, blk, 0, stream>>>(s1_bih2, s1_bhh2, 512, bg2, 512);
  bias_pad<<<2, blk, 0, stream>>>(s1_db,   nullptr, 257, bm1, 384);
  bias_pad<<<2, blk, 0, stream>>>(s2_bih1, s2_bhh1, 512, bg3, 512);
  bias_pad<<<2, blk, 0, stream>>>(s2_bih2, s2_bhh2, 512, bg4, 512);
  bias_pad<<<1, blk, 0, stream>>>(s2_db,   nullptr, 256, bm2, 256);

  convert_x<<<ceilb((long)BN*544), blk, 0, stream>>>(x, XShi, XSlo);
  unpack_state<<<ceilb((long)BN*NH), blk, 0, stream>>>(st1, h1hi, h1lo, C1, h2hi, h2lo, C2);

  // ---- rfft (bins 0..255) + Nyquist ----
  mfma_gemm<<<dim3(128,4), blk, 0, stream>>>(XShi, XSlo, 544, 512,
      fwdThi, fwdTlo, nullptr, nullptr, 0, 0, nullptr, nullptr,
      nullptr, RI, nullptr, nullptr, 514);
  nyq_kernel<<<BN/4, blk, 0, stream>>>(x, RI);
  magphase_kernel<<<ceilb((long)BN*288), blk, 0, stream>>>(RI, maghi, maglo);

  // ---- sep block 1 ----
  mfma_gemm<<<dim3(128,4), blk, 0, stream>>>(maghi, maglo, 288, 288,
      w11hi, w11lo, h1hi, h1lo, 128, 128, wh1hi, wh1lo,
      bg1, G, nullptr, nullptr, 512);
  lstm_cell<<<ceilb((long)BN*NH), blk, 0, stream>>>(G, C1, h1hi, h1lo, out_st1);
  mfma_gemm<<<dim3(128,4), blk, 0, stream>>>(h1hi, h1lo, 128, 128,
      w12hi, w12lo, h2hi, h2lo, 128, 128, wh2hi, wh2lo,
      bg2, G, nullptr, nullptr, 512);
  lstm_cell<<<ceilb((long)BN*NH), blk, 0, stream>>>(G, C2, h2hi, h2lo, out_st1 + (size_t)BN*NH*2);
  mfma_gemm<<<dim3(128,3), blk, 0, stream>>>(h2hi, h2lo, 128, 128,
      dw1hi, dw1lo, nullptr, nullptr, 0, 0, nullptr, nullptr,
      bm1, G, nullptr, nullptr, 512);
  est_build<<<ceilb((long)BN*272), blk, 0, stream>>>(G, 512, maghi, maglo, RI, XShi, XSlo);

  // ---- irfft -> Y1 planes (in G region) ----
  mfma_gemm<<<dim3(128,4), blk, 0, stream>>>(XShi, XSlo, 544, 544,
      invThi, invTlo, nullptr, nullptr, 0, 0, nullptr, nullptr,
      nullptr, nullptr, Y1hi, Y1lo, 512);

  // ---- encoder + LN ----
  mfma_gemm<<<dim3(128,2), blk, 0, stream>>>(Y1hi, Y1lo, 512, 512,
      encwhi, encwlo, nullptr, nullptr, 0, 0, nullptr, nullptr,
      nullptr, ENC, nullptr, nullptr, 256);
  ln_kernel<<<BN, 64, 0, stream>>>(ENC, ln_g, ln_b, ENCNhi, ENCNlo);

  // ---- sep block 2 ----
  unpack_state<<<ceilb((long)BN*NH), blk, 0, stream>>>(st2, h1hi, h1lo, C1, h2hi, h2lo, C2);
  mfma_gemm<<<dim3(128,4), blk, 0, stream>>>(ENCNhi, ENCNlo, 256, 256,
      w21hi, w21lo, h1hi, h1lo, 128, 128, wh3hi, wh3lo,
      bg3, G, nullptr, nullptr, 512);
  lstm_cell<<<ceilb((long)BN*NH), blk, 0, stream>>>(G, C1, h1hi, h1lo, out_st2);
  mfma_gemm<<<dim3(128,4), blk, 0, stream>>>(h1hi, h1lo, 128, 128,
      w22hi, w22lo, h2hi, h2lo, 128, 128, wh4hi, wh4lo,
      bg4, G, nullptr, nullptr, 512);
  lstm_cell<<<ceilb((long)BN*NH), blk, 0, stream>>>(G, C2, h2hi, h2lo, out_st2 + (size_t)BN*NH*2);
  mfma_gemm<<<dim3(128,2), blk, 0, stream>>>(h2hi, h2lo, 128, 128,
      dw2hi, dw2lo, nullptr, nullptr, 0, 0, nullptr, nullptr,
      bm2, G, nullptr, nullptr, 512);

  // ---- decoder ----
  dec_in<<<ceilb((long)BN*NE), blk, 0, stream>>>(G, ENC, Dhi, Dlo);
  mfma_gemm<<<dim3(128,4), blk, 0, stream>>>(Dhi, Dlo, 256, 256,
      decwhi, decwlo, nullptr, nullptr, 0, 0, nullptr, nullptr,
      nullptr, out_dec, nullptr, nullptr, 512);
}

// Round 2
// 431.004 us; speedup vs baseline: 1.0998x; 1.0757x over previous
//
#include <hip/hip_runtime.h>
#include <hip/hip_bf16.h>
#include <math.h>

static constexpr int BN   = 16384;
static constexpr int NFFT = 512;
static constexpr int NBIN = 257;
static constexpr int NH   = 128;
static constexpr int NE   = 256;
static constexpr float EPSF  = 1.1920929e-07f;
static constexpr float LNEPS = 1e-07f;

using short8  = __attribute__((ext_vector_type(8))) short;
using float4v = __attribute__((ext_vector_type(4))) float;

__device__ __forceinline__ float sigm(float x){ return 1.0f/(1.0f+expf(-x)); }
__device__ __forceinline__ ushort f2b(float v){
  __hip_bfloat16 b = __float2bfloat16(v);
  return *reinterpret_cast<ushort*>(&b);
}
__device__ __forceinline__ float b2f(ushort u){
  __hip_bfloat16 b = *reinterpret_cast<__hip_bfloat16*>(&u);
  return __bfloat162float(b);
}
__device__ __forceinline__ void split(float v, ushort* hi, ushort* lo){
  ushort h = f2b(v);
  *hi = h;
  *lo = f2b(v - b2f(h));
}

__device__ __forceinline__ void gload16(const ushort* g, ushort* l){
  __builtin_amdgcn_global_load_lds(
      (const __attribute__((address_space(1))) unsigned int*)g,
      (__attribute__((address_space(3))) unsigned int*)l,
      16, 0, 0);
}

// epilogue modes
enum { M_F32 = 0, M_PLANES = 1, M_LSTM = 2, M_EST = 3, M_DEC = 4, M_RFFT = 5 };

// ================= MFMA bf16x2 NT GEMM with fused epilogues =================
// C[row][col] = sum_k A[row][k]*B[col][k] (+ optional phase2 A2/B2)
// LDS tile: [128 rows][64 ushorts]; XOR swizzle folded into per-lane global
// source for global_load_lds (linear dest), read-side XOR (r&7)<<4.
// MODE_LSTM expects gate-PERMUTED weights/bias: col' = 128*(u>>5) + 32*g + (u&31).
template<int MODE>
__global__ __launch_bounds__(256)
void mfma_gemm(const ushort* __restrict__ Ahi, const ushort* __restrict__ Alo,
               int lda, int K,
               const ushort* __restrict__ Bhi, const ushort* __restrict__ Blo,
               const ushort* __restrict__ A2hi, const ushort* __restrict__ A2lo,
               int lda2, int K2,
               const ushort* __restrict__ B2hi, const ushort* __restrict__ B2lo,
               const float* __restrict__ bias,
               float* __restrict__ C, ushort* __restrict__ Chi,
               ushort* __restrict__ Clo, int ldc,
               const float* __restrict__ aux0,   // LSTM: c_in | EST: RI | DEC: ENC
               const ushort* __restrict__ aux1,  // EST: maghi
               const ushort* __restrict__ aux2,  // EST: maglo
               float* __restrict__ out0,         // LSTM: out_state (h,c pairs)
               ushort* __restrict__ o1,          // LSTM: h_hi | EST: XShi | DEC: Dhi | RFFT: maghi
               ushort* __restrict__ o2)          // lo counterparts
{
  __shared__ ushort smem[2][128][64];
  ushort (&As)[128][64] = smem[0];
  ushort (&Bs)[128][64] = smem[1];
  const int tid  = threadIdx.x;
  const int row0 = blockIdx.x * 128;
  const int col0 = blockIdx.y * 128;
  const int lane = tid & 63;
  const int wv   = tid >> 6;
  const int wr   = (wv >> 1) * 64;
  const int wc   = (wv & 1) * 64;
  const int fr   = lane & 15;
  const int quad = lane >> 4;

  const int lrow   = lane >> 3;        // 0..7
  const int pslot  = lane & 7;
  const int lslot  = pslot ^ lrow;     // logical slot this lane fetches
  const int kchunk = (lslot & 3) * 8;
  const bool isHi  = (lslot < 4);

  float4v acc[4][4];
  #pragma unroll
  for (int i = 0; i < 4; ++i)
    #pragma unroll
    for (int j = 0; j < 4; ++j)
      acc[i][j] = float4v{0.f, 0.f, 0.f, 0.f};

  const char* Ab = (const char*)&As[0][0];
  const char* Bb = (const char*)&Bs[0][0];

  #pragma unroll 1
  for (int phase = 0; phase < 2; ++phase) {
    const ushort* pAhi = phase ? A2hi : Ahi;
    const ushort* pAlo = phase ? A2lo : Alo;
    const ushort* pBhi = phase ? B2hi : Bhi;
    const ushort* pBlo = phase ? B2lo : Blo;
    const int ld_a = phase ? lda2 : lda;
    const int KK   = phase ? K2 : K;
    if (!pAhi) continue;

    const ushort* aplane = isHi ? pAhi : pAlo;
    const ushort* bplane = isHi ? pBhi : pBlo;
    size_t aoff[4], boff[4];
    #pragma unroll
    for (int si = 0; si < 4; ++si) {
      const int r = (wv * 4 + si) * 8 + lrow;
      aoff[si] = (size_t)(row0 + r) * ld_a + kchunk;
      boff[si] = (size_t)(col0 + r) * KK   + kchunk;
    }

    for (int kt = 0; kt < KK / 32; ++kt) {
      #pragma unroll
      for (int si = 0; si < 4; ++si) {
        gload16(aplane + aoff[si] + kt * 32, &As[(wv * 4 + si) * 8][0]);
        gload16(bplane + boff[si] + kt * 32, &Bs[(wv * 4 + si) * 8][0]);
      }
      asm volatile("s_waitcnt vmcnt(0)" ::: "memory");
      __syncthreads();

      short8 ah[4], al[4], bh[4], bl[4];
      #pragma unroll
      for (int i = 0; i < 4; ++i) {
        const int ra  = wr + i * 16 + fr;
        const int rb  = wc + i * 16 + fr;
        const int swa = (ra & 7) << 4;
        const int swb = (rb & 7) << 4;
        ah[i] = *(const short8*)(Ab + ra * 128 + ((quad << 4) ^ swa));
        al[i] = *(const short8*)(Ab + ra * 128 + ((64 | (quad << 4)) ^ swa));
        bh[i] = *(const short8*)(Bb + rb * 128 + ((quad << 4) ^ swb));
        bl[i] = *(const short8*)(Bb + rb * 128 + ((64 | (quad << 4)) ^ swb));
      }
      #pragma unroll
      for (int i = 0; i < 4; ++i)
        #pragma unroll
        for (int j = 0; j < 4; ++j) {
          acc[i][j] = __builtin_amdgcn_mfma_f32_16x16x32_bf16(ah[i], bh[j], acc[i][j], 0, 0, 0);
          acc[i][j] = __builtin_amdgcn_mfma_f32_16x16x32_bf16(ah[i], bl[j], acc[i][j], 0, 0, 0);
          acc[i][j] = __builtin_amdgcn_mfma_f32_16x16x32_bf16(al[i], bh[j], acc[i][j], 0, 0, 0);
        }
      __syncthreads();
    }
  }

  // ---- epilogues; C/D layout: col=lane&15 group, row=quad*4+reg ----
  if constexpr (MODE == M_F32) {
    #pragma unroll
    for (int j = 0; j < 4; ++j) {
      const int colb = col0 + wc + j * 16 + fr;
      const float bv = bias ? bias[colb] : 0.f;
      #pragma unroll
      for (int i = 0; i < 4; ++i)
        #pragma unroll
        for (int r = 0; r < 4; ++r) {
          const int row = row0 + wr + i * 16 + quad * 4 + r;
          C[(size_t)row * ldc + colb] = acc[i][j][r] + bv;
        }
    }
  } else if constexpr (MODE == M_PLANES) {
    #pragma unroll
    for (int j = 0; j < 4; ++j) {
      const int colb = col0 + wc + j * 16 + fr;
      #pragma unroll
      for (int i = 0; i < 4; ++i)
        #pragma unroll
        for (int r = 0; r < 4; ++r) {
          const int row = row0 + wr + i * 16 + quad * 4 + r;
          const size_t idx = (size_t)row * ldc + colb;
          split(acc[i][j][r], &Chi[idx], &Clo[idx]);
        }
    }
  } else if constexpr (MODE == M_RFFT) {
    // write RI f32, and mag planes for bins (pairs sit in adjacent lanes)
    #pragma unroll
    for (int j = 0; j < 4; ++j) {
      const int colb = col0 + wc + j * 16 + fr;
      #pragma unroll
      for (int i = 0; i < 4; ++i)
        #pragma unroll
        for (int r = 0; r < 4; ++r) {
          const int row = row0 + wr + i * 16 + quad * 4 + r;
          const float v = acc[i][j][r];
          C[(size_t)row * ldc + colb] = v;
          const float w = __shfl_xor(v, 1, 64);
          if (!(lane & 1)) {
            const int bin = colb >> 1;
            const float mg = sqrtf(fmaxf(v * v + w * w, EPSF));
            split(mg, &o1[(size_t)row * 288 + bin], &o2[(size_t)row * 288 + bin]);
          }
        }
    }
  } else if constexpr (MODE == M_EST) {
    // mask1-pre -> est stft planes [BN][544]
    #pragma unroll
    for (int j = 0; j < 4; ++j) {
      const int colg = col0 + wc + j * 16 + fr;   // bin index
      const float bv = bias[colg];
      #pragma unroll
      for (int i = 0; i < 4; ++i)
        #pragma unroll
        for (int r = 0; r < 4; ++r) {
          const int row = row0 + wr + i * 16 + quad * 4 + r;
          const size_t pp = (size_t)row * 544 + 2 * colg;
          if (colg < NBIN) {
            const float m   = sigm(acc[i][j][r] + bv);
            const float mag = b2f(aux1[(size_t)row * 288 + colg]) +
                              b2f(aux2[(size_t)row * 288 + colg]);
            const float e   = m * mag;
            const float rr  = aux0[(size_t)row * 514 + 2 * colg];
            const float im  = aux0[(size_t)row * 514 + 2 * colg + 1];
            const float re = rr + EPSF, ie = im + EPSF;
            const float hyp = fmaxf(sqrtf(re * re + ie * ie), 1e-35f);
            const float cr = e * re / hyp, ci = e * ie / hyp;
            split(cr, &o1[pp], &o2[pp]);
            split(ci, &o1[pp + 1], &o2[pp + 1]);
          } else if (colg < 272) {
            o1[pp] = 0; o1[pp + 1] = 0;
            o2[pp] = 0; o2[pp + 1] = 0;
          }
        }
    }
  } else if constexpr (MODE == M_DEC) {
    // mask2-pre -> D = sigmoid(pre)*ENC planes [BN][256]
    #pragma unroll
    for (int j = 0; j < 4; ++j) {
      const int colg = col0 + wc + j * 16 + fr;
      const float bv = bias[colg];
      #pragma unroll
      for (int i = 0; i < 4; ++i)
        #pragma unroll
        for (int r = 0; r < 4; ++r) {
          const int row = row0 + wr + i * 16 + quad * 4 + r;
          const size_t idx = (size_t)row * NE + colg;
          const float v = sigm(acc[i][j][r] + bv) * aux0[idx];
          split(v, &o1[idx], &o2[idx]);
        }
    }
  } else {
    // M_LSTM: gates permuted so this block's 128 cols = units ub..ub+31, gates 0..3
    float* Ep = (float*)&smem[0][0][0];   // 64 rows x 128 cols f32 = 32 KB
    const int ub = blockIdx.y << 5;
    #pragma unroll 1
    for (int p = 0; p < 2; ++p) {
      __syncthreads();
      if (wr == p * 64) {
        #pragma unroll
        for (int j = 0; j < 4; ++j) {
          const int cl = wc + j * 16 + fr;
          const float bv = bias[col0 + cl];
          #pragma unroll
          for (int i = 0; i < 4; ++i)
            #pragma unroll
            for (int r = 0; r < 4; ++r)
              Ep[(i * 16 + quad * 4 + r) * 128 + cl] = acc[i][j][r] + bv;
        }
      }
      __syncthreads();
      #pragma unroll
      for (int k = 0; k < 8; ++k) {
        const int cell = tid + 256 * k;        // 0..2047
        const int ul = cell & 31;
        const int er = cell >> 5;              // 0..63
        const int row = row0 + p * 64 + er;
        const int unit = ub + ul;
        const float gi = Ep[er * 128 + ul];
        const float gf = Ep[er * 128 + 32 + ul];
        const float gc = Ep[er * 128 + 64 + ul];
        const float go = Ep[er * 128 + 96 + ul];
        const float cp = aux0[(size_t)row * NH + unit];
        const float cn = sigm(gf) * cp + sigm(gi) * tanhf(gc);
        const float hn = sigm(go) * tanhf(cn);
        const size_t hidx = (size_t)row * NH + unit;
        split(hn, &o1[hidx], &o2[hidx]);
        float2 hc; hc.x = hn; hc.y = cn;
        *(float2*)(out0 + 2 * hidx) = hc;
      }
    }
  }
}

// ================= weight / bias prep =================
__global__ void wconv(const float* __restrict__ src, int M0, int K0,
                      ushort* __restrict__ hi, ushort* __restrict__ lo,
                      int Mp, int Kp){
  int idx = blockIdx.x * blockDim.x + threadIdx.x;
  if (idx >= Mp * Kp) return;
  int r = idx / Kp, c = idx - r * Kp;
  float v = (r < M0 && c < K0) ? src[(size_t)r * K0 + c] : 0.f;
  split(v, &hi[idx], &lo[idx]);
}

// gate-permuted weight conversion: dst row r' <- src row g*128+u,
// r' = 128*(u>>5) + 32*g + (u&31)  <=>  y=r'>>7, g=(r'>>5)&3, u=32y+(r'&31)
__global__ void wconv_g(const float* __restrict__ src, int K0,
                        ushort* __restrict__ hi, ushort* __restrict__ lo, int Kp){
  int idx = blockIdx.x * blockDim.x + threadIdx.x;
  if (idx >= 512 * Kp) return;
  int rp = idx / Kp, c = idx - rp * Kp;
  int y = rp >> 7, g = (rp >> 5) & 3, u = (y << 5) | (rp & 31);
  float v = (c < K0) ? src[(size_t)(g * 128 + u) * K0 + c] : 0.f;
  split(v, &hi[idx], &lo[idx]);
}

__global__ void bias_pad(const float* __restrict__ s1, const float* __restrict__ s2,
                         int L, float* __restrict__ dst, int Lp){
  int idx = blockIdx.x * blockDim.x + threadIdx.x;
  if (idx >= Lp) return;
  float v = 0.f;
  if (idx < L) { v = s1[idx]; if (s2) v += s2[idx]; }
  dst[idx] = v;
}

__global__ void bias_g(const float* __restrict__ s1, const float* __restrict__ s2,
                       float* __restrict__ dst){
  int rp = blockIdx.x * blockDim.x + threadIdx.x;
  if (rp >= 512) return;
  int y = rp >> 7, g = (rp >> 5) & 3, u = (y << 5) | (rp & 31);
  int sr = g * 128 + u;
  dst[rp] = s1[sr] + s2[sr];
}

__global__ void fill_fwd(ushort* __restrict__ hi, ushort* __restrict__ lo){
  int idx = blockIdx.x * blockDim.x + threadIdx.x;
  if (idx >= 512 * 512) return;
  int c = idx >> 9, n = idx & 511;
  int k = c >> 1, m = (k * n) & 511;
  float th = (float)m * (6.283185307179586f / 512.0f);
  float s, co; sincosf(th, &s, &co);
  float v = (c & 1) ? -s : co;
  split(v, &hi[idx], &lo[idx]);
}

__global__ void fill_inv(ushort* __restrict__ hi, ushort* __restrict__ lo){
  int idx = blockIdx.x * blockDim.x + threadIdx.x;
  if (idx >= 512 * 544) return;
  int n = idx / 544, c = idx - n * 544;
  float v = 0.f;
  if (c < 512) {
    int k = c >> 1, m = (k * n) & 511;
    float th = (float)m * (6.283185307179586f / 512.0f);
    float s, co; sincosf(th, &s, &co);
    float w = (k == 0) ? (1.0f / 512.0f) : (2.0f / 512.0f);
    v = (c & 1) ? -w * s : w * co;
  } else if (c == 512) {
    v = ((n & 1) ? -1.0f : 1.0f) / 512.0f;
  }
  split(v, &hi[idx], &lo[idx]);
}

// ================= elementwise =================
__global__ void convert_x(const float* __restrict__ x,
                          ushort* __restrict__ hi, ushort* __restrict__ lo){
  int idx = blockIdx.x * blockDim.x + threadIdx.x;
  if (idx >= BN * 544) return;
  int r = idx / 544, c = idx - r * 544;
  float v = (c < 512) ? x[(size_t)r * 512 + c] : 0.f;
  split(v, &hi[idx], &lo[idx]);
}

// Nyquist: RI[n][512]=sum x*(-1)^i, RI[n][513]=0, mag bins 256..287
__global__ void nyq_kernel(const float* __restrict__ x, float* __restrict__ RI,
                           ushort* __restrict__ mhi, ushort* __restrict__ mlo){
  int row  = blockIdx.x * 4 + (threadIdx.x >> 6);
  int lane = threadIdx.x & 63;
  const float* xr = x + (size_t)row * 512;
  float s = 0.f;
  #pragma unroll
  for (int i = 0; i < 8; ++i) {
    int n = lane + 64 * i;
    float v = xr[n];
    s += (n & 1) ? -v : v;
  }
  #pragma unroll
  for (int off = 32; off >= 1; off >>= 1) s += __shfl_xor(s, off, 64);
  if (lane == 0) {
    RI[(size_t)row * 514 + 512] = s;
    RI[(size_t)row * 514 + 513] = 0.f;
  }
  if (lane < 32) {
    float mg = (lane == 0) ? sqrtf(fmaxf(s * s, EPSF)) : 0.f;
    size_t p = (size_t)row * 288 + 256 + lane;
    split(mg, &mhi[p], &mlo[p]);
  }
}

// in_state (2,BN,NH,2) f32 -> H hi/lo planes + C f32 (both layers)
__global__ void unpack_state(const float* __restrict__ st,
                             ushort* __restrict__ h1hi, ushort* __restrict__ h1lo,
                             float* __restrict__ c1,
                             ushort* __restrict__ h2hi, ushort* __restrict__ h2lo,
                             float* __restrict__ c2){
  int idx = blockIdx.x * blockDim.x + threadIdx.x;
  if (idx >= BN * NH) return;
  split(st[(size_t)idx * 2], &h1hi[idx], &h1lo[idx]);
  c1[idx] = st[(size_t)idx * 2 + 1];
  size_t off = (size_t)BN * NH * 2;
  split(st[off + (size_t)idx * 2], &h2hi[idx], &h2lo[idx]);
  c2[idx] = st[off + (size_t)idx * 2 + 1];
}

// LayerNorm over 256 -> ENCN hi/lo planes
__global__ void ln_kernel(const float* __restrict__ ENC,
                          const float* __restrict__ gamma,
                          const float* __restrict__ beta,
                          ushort* __restrict__ ohi, ushort* __restrict__ olo){
  int row = blockIdx.x;
  int t = threadIdx.x;   // 64
  const float* e = ENC + (size_t)row * NE;
  float v[4]; float s = 0.f;
  #pragma unroll
  for (int i = 0; i < 4; ++i) { v[i] = e[t + 64 * i]; s += v[i]; }
  #pragma unroll
  for (int off = 32; off >= 1; off >>= 1) s += __shfl_xor(s, off, 64);
  float mean = s * (1.0f / NE);
  float d[4]; float ss = 0.f;
  #pragma unroll
  for (int i = 0; i < 4; ++i) { d[i] = v[i] - mean; ss += d[i] * d[i]; }
  #pragma unroll
  for (int off = 32; off >= 1; off >>= 1) ss += __shfl_xor(ss, off, 64);
  float inv = 1.0f / sqrtf(ss * (1.0f / NE) + LNEPS);
  #pragma unroll
  for (int i = 0; i < 4; ++i) {
    int col = t + 64 * i;
    float o = d[i] * inv * gamma[col] + beta[col];
    size_t p = (size_t)row * NE + col;
    split(o, &ohi[p], &olo[p]);
  }
}

// ================= launch =================
extern "C" void kernel_launch(void* const* d_in, const int* in_sizes, int n_in,
                              void* d_out, int out_size, void* d_ws, size_t ws_size,
                              hipStream_t stream)
{
  const float* x       = (const float*)d_in[0];
  const float* st1     = (const float*)d_in[1];
  const float* st2     = (const float*)d_in[2];
  const float* s1_wih1 = (const float*)d_in[3];
  const float* s1_whh1 = (const float*)d_in[4];
  const float* s1_bih1 = (const float*)d_in[5];
  const float* s1_bhh1 = (const float*)d_in[6];
  const float* s1_wih2 = (const float*)d_in[7];
  const float* s1_whh2 = (const float*)d_in[8];
  const float* s1_bih2 = (const float*)d_in[9];
  const float* s1_bhh2 = (const float*)d_in[10];
  const float* s1_dw   = (const float*)d_in[11];
  const float* s1_db   = (const float*)d_in[12];
  const float* enc_w   = (const float*)d_in[13];
  const float* ln_g    = (const float*)d_in[14];
  const float* ln_b    = (const float*)d_in[15];
  const float* s2_wih1 = (const float*)d_in[16];
  const float* s2_whh1 = (const float*)d_in[17];
  const float* s2_bih1 = (const float*)d_in[18];
  const float* s2_bhh1 = (const float*)d_in[19];
  const float* s2_wih2 = (const float*)d_in[20];
  const float* s2_whh2 = (const float*)d_in[21];
  const float* s2_bih2 = (const float*)d_in[22];
  const float* s2_bhh2 = (const float*)d_in[23];
  const float* s2_dw   = (const float*)d_in[24];
  const float* s2_db   = (const float*)d_in[25];
  const float* dec_w   = (const float*)d_in[26];

  float* out_dec = (float*)d_out;
  float* out_st1 = out_dec + (size_t)BN * NFFT;
  float* out_st2 = out_st1 + (size_t)2 * BN * NH * 2;

  // ---- workspace ----
  char* base = (char*)d_ws;
  size_t off = 0;
  auto alloc = [&](size_t bytes) -> void* {
    off = (off + 255) & ~(size_t)255;
    void* p = base + off;
    off += bytes;
    return p;
  };
  ushort* fwdThi = (ushort*)alloc((size_t)512 * 512 * 2);
  ushort* fwdTlo = (ushort*)alloc((size_t)512 * 512 * 2);
  ushort* invThi = (ushort*)alloc((size_t)512 * 544 * 2);
  ushort* invTlo = (ushort*)alloc((size_t)512 * 544 * 2);
  ushort* XShi   = (ushort*)alloc((size_t)BN * 544 * 2);
  ushort* XSlo   = (ushort*)alloc((size_t)BN * 544 * 2);
  float*  RI     = (float*) alloc((size_t)BN * 514 * 4);
  float*  G      = (float*) alloc((size_t)BN * 512 * 4);  // Y1 planes region
  char*   R1     = (char*)  alloc((size_t)BN * NE * 4 * 2);
  ushort* h1hi   = (ushort*)alloc((size_t)BN * NH * 2);
  ushort* h1lo   = (ushort*)alloc((size_t)BN * NH * 2);
  ushort* h2hi   = (ushort*)alloc((size_t)BN * NH * 2);
  ushort* h2lo   = (ushort*)alloc((size_t)BN * NH * 2);
  ushort* h1nhi  = (ushort*)alloc((size_t)BN * NH * 2);
  ushort* h1nlo  = (ushort*)alloc((size_t)BN * NH * 2);
  ushort* h2nhi  = (ushort*)alloc((size_t)BN * NH * 2);
  ushort* h2nlo  = (ushort*)alloc((size_t)BN * NH * 2);
  float*  C1     = (float*) alloc((size_t)BN * NH * 4);
  float*  C2     = (float*) alloc((size_t)BN * NH * 4);
  ushort* w11hi = (ushort*)alloc((size_t)512*288*2); ushort* w11lo = (ushort*)alloc((size_t)512*288*2);
  ushort* wh1hi = (ushort*)alloc((size_t)512*128*2); ushort* wh1lo = (ushort*)alloc((size_t)512*128*2);
  ushort* w12hi = (ushort*)alloc((size_t)512*128*2); ushort* w12lo = (ushort*)alloc((size_t)512*128*2);
  ushort* wh2hi = (ushort*)alloc((size_t)512*128*2); ushort* wh2lo = (ushort*)alloc((size_t)512*128*2);
  ushort* dw1hi = (ushort*)alloc((size_t)384*128*2); ushort* dw1lo = (ushort*)alloc((size_t)384*128*2);
  ushort* encwhi= (ushort*)alloc((size_t)256*512*2); ushort* encwlo= (ushort*)alloc((size_t)256*512*2);
  ushort* w21hi = (ushort*)alloc((size_t)512*256*2); ushort* w21lo = (ushort*)alloc((size_t)512*256*2);
  ushort* wh3hi = (ushort*)alloc((size_t)512*128*2); ushort* wh3lo = (ushort*)alloc((size_t)512*128*2);
  ushort* w22hi = (ushort*)alloc((size_t)512*128*2); ushort* w22lo = (ushort*)alloc((size_t)512*128*2);
  ushort* wh4hi = (ushort*)alloc((size_t)512*128*2); ushort* wh4lo = (ushort*)alloc((size_t)512*128*2);
  ushort* dw2hi = (ushort*)alloc((size_t)256*128*2); ushort* dw2lo = (ushort*)alloc((size_t)256*128*2);
  ushort* decwhi= (ushort*)alloc((size_t)512*256*2); ushort* decwlo= (ushort*)alloc((size_t)512*256*2);
  float* bg1 = (float*)alloc(512*4); float* bg2 = (float*)alloc(512*4);
  float* bm1 = (float*)alloc(384*4);
  float* bg3 = (float*)alloc(512*4); float* bg4 = (float*)alloc(512*4);
  float* bm2 = (float*)alloc(256*4);
  (void)ws_size; (void)in_sizes; (void)n_in; (void)out_size;

  // region overlays
  ushort* maghi  = (ushort*)R1;                              // [BN][288]
  ushort* maglo  = (ushort*)(R1 + (size_t)BN * 288 * 2);
  float*  ENC    = (float*)R1;                               // [BN][256] (MAG dead)
  ushort* ENCNhi = (ushort*)(R1 + (size_t)BN * NE * 4);      // [BN][256]
  ushort* ENCNlo = (ushort*)(R1 + (size_t)BN * NE * 4 + (size_t)BN * NE * 2);
  ushort* Dhi    = ENCNhi;                                   // dec-in planes
  ushort* Dlo    = ENCNlo;
  ushort* Y1hi   = (ushort*)G;                               // [BN][512]
  ushort* Y1lo   = (ushort*)G + (size_t)BN * 512;

  const dim3 blk(256);
  auto ceilb = [](long n){ return (int)((n + 255) / 256); };

  // ---- prep ----
  fill_fwd<<<ceilb((long)512*512), blk, 0, stream>>>(fwdThi, fwdTlo);
  fill_inv<<<ceilb((long)512*544), blk, 0, stream>>>(invThi, invTlo);
  wconv_g<<<ceilb((long)512*288), blk, 0, stream>>>(s1_wih1, 257, w11hi, w11lo, 288);
  wconv_g<<<ceilb((long)512*128), blk, 0, stream>>>(s1_whh1, 128, wh1hi, wh1lo, 128);
  wconv_g<<<ceilb((long)512*128), blk, 0, stream>>>(s1_wih2, 128, w12hi, w12lo, 128);
  wconv_g<<<ceilb((long)512*128), blk, 0, stream>>>(s1_whh2, 128, wh2hi, wh2lo, 128);
  wconv<<<ceilb((long)384*128), blk, 0, stream>>>(s1_dw,   257, 128, dw1hi, dw1lo, 384, 128);
  wconv<<<ceilb((long)256*512), blk, 0, stream>>>(enc_w,   256, 512, encwhi, encwlo, 256, 512);
  wconv_g<<<ceilb((long)512*256), blk, 0, stream>>>(s2_wih1, 256, w21hi, w21lo, 256);
  wconv_g<<<ceilb((long)512*128), blk, 0, stream>>>(s2_whh1, 128, wh3hi, wh3lo, 128);
  wconv_g<<<ceilb((long)512*128), blk, 0, stream>>>(s2_wih2, 128, w22hi, w22lo, 128);
  wconv_g<<<ceilb((long)512*128), blk, 0, stream>>>(s2_whh2, 128, wh4hi, wh4lo, 128);
  wconv<<<ceilb((long)256*128), blk, 0, stream>>>(s2_dw,   256, 128, dw2hi, dw2lo, 256, 128);
  wconv<<<ceilb((long)512*256), blk, 0, stream>>>(dec_w,   512, 256, decwhi, decwlo, 512, 256);
  bias_g<<<2, blk, 0, stream>>>(s1_bih1, s1_bhh1, bg1);
  bias_g<<<2, blk, 0, stream>>>(s1_bih2, s1_bhh2, bg2);
  bias_pad<<<2, blk, 0, stream>>>(s1_db,   nullptr, 257, bm1, 384);
  bias_g<<<2, blk, 0, stream>>>(s2_bih1, s2_bhh1, bg3);
  bias_g<<<2, blk, 0, stream>>>(s2_bih2, s2_bhh2, bg4);
  bias_pad<<<1, blk, 0, stream>>>(s2_db,   nullptr, 256, bm2, 256);

  convert_x<<<ceilb((long)BN*544), blk, 0, stream>>>(x, XShi, XSlo);
  unpack_state<<<ceilb((long)BN*NH), blk, 0, stream>>>(st1, h1hi, h1lo, C1, h2hi, h2lo, C2);

  // ---- rfft (+fused magphase) + Nyquist ----
  mfma_gemm<M_RFFT><<<dim3(128,4), blk, 0, stream>>>(XShi, XSlo, 544, 512,
      fwdThi, fwdTlo, nullptr, nullptr, 0, 0, nullptr, nullptr,
      nullptr, RI, nullptr, nullptr, 514,
      nullptr, nullptr, nullptr, nullptr, maghi, maglo);
  nyq_kernel<<<BN/4, blk, 0, stream>>>(x, RI, maghi, maglo);

  // ---- sep block 1 (fused LSTM epilogues) ----
  mfma_gemm<M_LSTM><<<dim3(128,4), blk, 0, stream>>>(maghi, maglo, 288, 288,
      w11hi, w11lo, h1hi, h1lo, 128, 128, wh1hi, wh1lo,
      bg1, nullptr, nullptr, nullptr, 0,
      C1, nullptr, nullptr, out_st1, h1nhi, h1nlo);
  mfma_gemm<M_LSTM><<<dim3(128,4), blk, 0, stream>>>(h1nhi, h1nlo, 128, 128,
      w12hi, w12lo, h2hi, h2lo, 128, 128, wh2hi, wh2lo,
      bg2, nullptr, nullptr, nullptr, 0,
      C2, nullptr, nullptr, out_st1 + (size_t)BN*NH*2, h2nhi, h2nlo);
  // ---- mask1 + fused est_build -> XS planes ----
  mfma_gemm<M_EST><<<dim3(128,3), blk, 0, stream>>>(h2nhi, h2nlo, 128, 128,
      dw1hi, dw1lo, nullptr, nullptr, 0, 0, nullptr, nullptr,
      bm1, nullptr, nullptr, nullptr, 0,
      RI, maghi, maglo, nullptr, XShi, XSlo);

  // ---- irfft -> Y1 planes ----
  mfma_gemm<M_PLANES><<<dim3(128,4), blk, 0, stream>>>(XShi, XSlo, 544, 544,
      invThi, invTlo, nullptr, nullptr, 0, 0, nullptr, nullptr,
      nullptr, nullptr, Y1hi, Y1lo, 512,
      nullptr, nullptr, nullptr, nullptr, nullptr, nullptr);

  // ---- encoder + LN ----
  mfma_gemm<M_F32><<<dim3(128,2), blk, 0, stream>>>(Y1hi, Y1lo, 512, 512,
      encwhi, encwlo, nullptr, nullptr, 0, 0, nullptr, nullptr,
      nullptr, ENC, nullptr, nullptr, 256,
      nullptr, nullptr, nullptr, nullptr, nullptr, nullptr);
  ln_kernel<<<BN, 64, 0, stream>>>(ENC, ln_g, ln_b, ENCNhi, ENCNlo);

  // ---- sep block 2 ----
  unpack_state<<<ceilb((long)BN*NH), blk, 0, stream>>>(st2, h1hi, h1lo, C1, h2hi, h2lo, C2);
  mfma_gemm<M_LSTM><<<dim3(128,4), blk, 0, stream>>>(ENCNhi, ENCNlo, 256, 256,
      w21hi, w21lo, h1hi, h1lo, 128, 128, wh3hi, wh3lo,
      bg3, nullptr, nullptr, nullptr, 0,
      C1, nullptr, nullptr, out_st2, h1nhi, h1nlo);
  mfma_gemm<M_LSTM><<<dim3(128,4), blk, 0, stream>>>(h1nhi, h1nlo, 128, 128,
      w22hi, w22lo, h2hi, h2lo, 128, 128, wh4hi, wh4lo,
      bg4, nullptr, nullptr, nullptr, 0,
      C2, nullptr, nullptr, out_st2 + (size_t)BN*NH*2, h2nhi, h2nlo);
  // ---- mask2 + fused dec_in -> D planes ----
  mfma_gemm<M_DEC><<<dim3(128,2), blk, 0, stream>>>(h2nhi, h2nlo, 128, 128,
      dw2hi, dw2lo, nullptr, nullptr, 0, 0, nullptr, nullptr,
      bm2, nullptr, nullptr, nullptr, 0,
      ENC, nullptr, nullptr, nullptr, Dhi, Dlo);

  // ---- decoder ----
  mfma_gemm<M_F32><<<dim3(128,4), blk, 0, stream>>>(Dhi, Dlo, 256, 256,
      decwhi, decwlo, nullptr, nullptr, 0, 0, nullptr, nullptr,
      nullptr, out_dec, nullptr, nullptr, 512,
      nullptr, nullptr, nullptr, nullptr, nullptr, nullptr);
}

// Round 3
// 428.886 us; speedup vs baseline: 1.1052x; 1.0049x over previous
//
#include <hip/hip_runtime.h>
#include <hip/hip_bf16.h>
#include <math.h>

static constexpr int BN   = 16384;
static constexpr int NFFT = 512;
static constexpr int NBIN = 257;
static constexpr int NH   = 128;
static constexpr int NE   = 256;
static constexpr float EPSF  = 1.1920929e-07f;
static constexpr float LNEPS = 1e-07f;

using short8  = __attribute__((ext_vector_type(8))) short;
using float4v = __attribute__((ext_vector_type(4))) float;

__device__ __forceinline__ float sigm(float x){ return 1.0f/(1.0f+expf(-x)); }
__device__ __forceinline__ ushort f2b(float v){
  __hip_bfloat16 b = __float2bfloat16(v);
  return *reinterpret_cast<ushort*>(&b);
}
__device__ __forceinline__ float b2f(ushort u){
  __hip_bfloat16 b = *reinterpret_cast<__hip_bfloat16*>(&u);
  return __bfloat162float(b);
}
__device__ __forceinline__ void split(float v, ushort* hi, ushort* lo){
  ushort h = f2b(v);
  *hi = h;
  *lo = f2b(v - b2f(h));
}

__device__ __forceinline__ void gload16(const ushort* g, ushort* l){
  __builtin_amdgcn_global_load_lds(
      (const __attribute__((address_space(1))) unsigned int*)g,
      (__attribute__((address_space(3))) unsigned int*)l,
      16, 0, 0);
}

// epilogue modes
enum { M_F32 = 0, M_PLANES = 1, M_LSTM = 2, M_EST = 3, M_DEC = 4, M_RFFT = 5 };

// ================= MFMA bf16x2 NT GEMM, 2-phase dbuf pipeline =================
// C[row][col] = sum_k A[row][k]*B[col][k] (+ optional phase2 A2/B2)
// LDS: double-buffered [2][A|B][128][64]; XOR swizzle folded into per-lane
// global source for global_load_lds (linear dest), read-side XOR (r&7)<<4.
// K-loop: stage(t+1) -> vmcnt(8) -> s_barrier -> ds_read+MFMA(t) ->
// lgkmcnt(0) -> s_barrier.  Counted vmcnt keeps next-tile loads in flight
// across the barrier (no full drain).
// MODE_LSTM expects gate-PERMUTED weights/bias: col' = 128*(u>>5)+32*g+(u&31).
template<int MODE>
__global__ __launch_bounds__(256)
void mfma_gemm(const ushort* __restrict__ Ahi, const ushort* __restrict__ Alo,
               int lda, int K,
               const ushort* __restrict__ Bhi, const ushort* __restrict__ Blo,
               const ushort* __restrict__ A2hi, const ushort* __restrict__ A2lo,
               int lda2, int K2,
               const ushort* __restrict__ B2hi, const ushort* __restrict__ B2lo,
               const float* __restrict__ bias,
               float* __restrict__ C, ushort* __restrict__ Chi,
               ushort* __restrict__ Clo, int ldc,
               const float* __restrict__ aux0,   // LSTM: c_in | EST: RI | DEC: ENC
               const ushort* __restrict__ aux1,  // EST: maghi
               const ushort* __restrict__ aux2,  // EST: maglo
               float* __restrict__ out0,         // LSTM: out_state (h,c pairs)
               ushort* __restrict__ o1,          // LSTM: h_hi | EST: XShi | DEC: Dhi | RFFT: maghi
               ushort* __restrict__ o2)          // lo counterparts
{
  __shared__ ushort smem[2][2][128][64];   // [buf][A|B][row][64] = 64 KB
  const int tid  = threadIdx.x;
  const int row0 = blockIdx.x * 128;
  const int col0 = blockIdx.y * 128;
  const int lane = tid & 63;
  const int wv   = tid >> 6;
  const int wr   = (wv >> 1) * 64;
  const int wc   = (wv & 1) * 64;
  const int fr   = lane & 15;
  const int quad = lane >> 4;

  const int lrow   = lane >> 3;        // 0..7
  const int pslot  = lane & 7;
  const int lslot  = pslot ^ lrow;     // logical slot this lane fetches
  const int kchunk = (lslot & 3) * 8;
  const bool isHi  = (lslot < 4);

  float4v acc[4][4];
  #pragma unroll
  for (int i = 0; i < 4; ++i)
    #pragma unroll
    for (int j = 0; j < 4; ++j)
      acc[i][j] = float4v{0.f, 0.f, 0.f, 0.f};

  const int nt0 = K / 32;
  const int nt1 = A2hi ? (K2 / 32) : 0;
  const int nt  = nt0 + nt1;

  const ushort* ap0 = isHi ? Ahi : Alo;
  const ushort* bp0 = isHi ? Bhi : Blo;
  const ushort* ap1 = isHi ? A2hi : A2lo;
  const ushort* bp1 = isHi ? B2hi : B2lo;
  size_t a0[4], b0[4], a1[4], b1[4];
  #pragma unroll
  for (int si = 0; si < 4; ++si) {
    const int r = (wv * 4 + si) * 8 + lrow;
    a0[si] = (size_t)(row0 + r) * lda  + kchunk;
    b0[si] = (size_t)(col0 + r) * K    + kchunk;
    a1[si] = (size_t)(row0 + r) * lda2 + kchunk;
    b1[si] = (size_t)(col0 + r) * K2   + kchunk;
  }

  auto stage = [&](int tt, int b) {
    if (tt < nt0) {
      #pragma unroll
      for (int si = 0; si < 4; ++si) {
        gload16(ap0 + a0[si] + (size_t)tt * 32, &smem[b][0][(wv * 4 + si) * 8][0]);
        gload16(bp0 + b0[si] + (size_t)tt * 32, &smem[b][1][(wv * 4 + si) * 8][0]);
      }
    } else {
      const int kt = tt - nt0;
      #pragma unroll
      for (int si = 0; si < 4; ++si) {
        gload16(ap1 + a1[si] + (size_t)kt * 32, &smem[b][0][(wv * 4 + si) * 8][0]);
        gload16(bp1 + b1[si] + (size_t)kt * 32, &smem[b][1][(wv * 4 + si) * 8][0]);
      }
    }
  };

  stage(0, 0);
  #pragma unroll 1
  for (int t = 0; t < nt; ++t) {
    const int cur = t & 1;
    if (t + 1 < nt) {
      stage(t + 1, cur ^ 1);                      // 8 loads in flight for next tile
      asm volatile("s_waitcnt vmcnt(8)" ::: "memory");   // current tile's 8 done
    } else {
      asm volatile("s_waitcnt vmcnt(0)" ::: "memory");
    }
    __builtin_amdgcn_s_barrier();                 // all waves' cur tile in LDS
    __builtin_amdgcn_sched_barrier(0);

    const char* Ab = (const char*)smem[cur][0];
    const char* Bb = (const char*)smem[cur][1];
    short8 ah[4], al[4], bh[4], bl[4];
    #pragma unroll
    for (int i = 0; i < 4; ++i) {
      const int ra  = wr + i * 16 + fr;
      const int rb  = wc + i * 16 + fr;
      const int swa = (ra & 7) << 4;
      const int swb = (rb & 7) << 4;
      ah[i] = *(const short8*)(Ab + ra * 128 + ((quad << 4) ^ swa));
      al[i] = *(const short8*)(Ab + ra * 128 + ((64 | (quad << 4)) ^ swa));
      bh[i] = *(const short8*)(Bb + rb * 128 + ((quad << 4) ^ swb));
      bl[i] = *(const short8*)(Bb + rb * 128 + ((64 | (quad << 4)) ^ swb));
    }
    #pragma unroll
    for (int i = 0; i < 4; ++i)
      #pragma unroll
      for (int j = 0; j < 4; ++j) {
        acc[i][j] = __builtin_amdgcn_mfma_f32_16x16x32_bf16(ah[i], bh[j], acc[i][j], 0, 0, 0);
        acc[i][j] = __builtin_amdgcn_mfma_f32_16x16x32_bf16(ah[i], bl[j], acc[i][j], 0, 0, 0);
        acc[i][j] = __builtin_amdgcn_mfma_f32_16x16x32_bf16(al[i], bh[j], acc[i][j], 0, 0, 0);
      }
    asm volatile("s_waitcnt lgkmcnt(0)" ::: "memory");   // ds_reads complete
    __builtin_amdgcn_sched_barrier(0);
    __builtin_amdgcn_s_barrier();                 // release cur buf for overwrite
  }

  // ---- epilogues; C/D layout: col=lane&15 group, row=quad*4+reg ----
  if constexpr (MODE == M_F32) {
    #pragma unroll
    for (int j = 0; j < 4; ++j) {
      const int colb = col0 + wc + j * 16 + fr;
      const float bv = bias ? bias[colb] : 0.f;
      #pragma unroll
      for (int i = 0; i < 4; ++i)
        #pragma unroll
        for (int r = 0; r < 4; ++r) {
          const int row = row0 + wr + i * 16 + quad * 4 + r;
          C[(size_t)row * ldc + colb] = acc[i][j][r] + bv;
        }
    }
  } else if constexpr (MODE == M_PLANES) {
    #pragma unroll
    for (int j = 0; j < 4; ++j) {
      const int colb = col0 + wc + j * 16 + fr;
      #pragma unroll
      for (int i = 0; i < 4; ++i)
        #pragma unroll
        for (int r = 0; r < 4; ++r) {
          const int row = row0 + wr + i * 16 + quad * 4 + r;
          const size_t idx = (size_t)row * ldc + colb;
          split(acc[i][j][r], &Chi[idx], &Clo[idx]);
        }
    }
  } else if constexpr (MODE == M_RFFT) {
    #pragma unroll
    for (int j = 0; j < 4; ++j) {
      const int colb = col0 + wc + j * 16 + fr;
      #pragma unroll
      for (int i = 0; i < 4; ++i)
        #pragma unroll
        for (int r = 0; r < 4; ++r) {
          const int row = row0 + wr + i * 16 + quad * 4 + r;
          const float v = acc[i][j][r];
          C[(size_t)row * ldc + colb] = v;
          const float w = __shfl_xor(v, 1, 64);
          if (!(lane & 1)) {
            const int bin = colb >> 1;
            const float mg = sqrtf(fmaxf(v * v + w * w, EPSF));
            split(mg, &o1[(size_t)row * 288 + bin], &o2[(size_t)row * 288 + bin]);
          }
        }
    }
  } else if constexpr (MODE == M_EST) {
    #pragma unroll
    for (int j = 0; j < 4; ++j) {
      const int colg = col0 + wc + j * 16 + fr;   // bin index
      const float bv = bias[colg];
      #pragma unroll
      for (int i = 0; i < 4; ++i)
        #pragma unroll
        for (int r = 0; r < 4; ++r) {
          const int row = row0 + wr + i * 16 + quad * 4 + r;
          const size_t pp = (size_t)row * 544 + 2 * colg;
          if (colg < NBIN) {
            const float m   = sigm(acc[i][j][r] + bv);
            const float mag = b2f(aux1[(size_t)row * 288 + colg]) +
                              b2f(aux2[(size_t)row * 288 + colg]);
            const float e   = m * mag;
            const float rr  = aux0[(size_t)row * 514 + 2 * colg];
            const float im  = aux0[(size_t)row * 514 + 2 * colg + 1];
            const float re = rr + EPSF, ie = im + EPSF;
            const float hyp = fmaxf(sqrtf(re * re + ie * ie), 1e-35f);
            const float cr = e * re / hyp, ci = e * ie / hyp;
            split(cr, &o1[pp], &o2[pp]);
            split(ci, &o1[pp + 1], &o2[pp + 1]);
          } else if (colg < 272) {
            o1[pp] = 0; o1[pp + 1] = 0;
            o2[pp] = 0; o2[pp + 1] = 0;
          }
        }
    }
  } else if constexpr (MODE == M_DEC) {
    #pragma unroll
    for (int j = 0; j < 4; ++j) {
      const int colg = col0 + wc + j * 16 + fr;
      const float bv = bias[colg];
      #pragma unroll
      for (int i = 0; i < 4; ++i)
        #pragma unroll
        for (int r = 0; r < 4; ++r) {
          const int row = row0 + wr + i * 16 + quad * 4 + r;
          const size_t idx = (size_t)row * NE + colg;
          const float v = sigm(acc[i][j][r] + bv) * aux0[idx];
          split(v, &o1[idx], &o2[idx]);
        }
    }
  } else {
    // M_LSTM: gates permuted so this block's 128 cols = units ub..ub+31, gates 0..3
    float* Ep = (float*)&smem[0][0][0][0];   // 64 rows x 128 cols f32 = 32 KB
    const int ub = blockIdx.y << 5;
    #pragma unroll 1
    for (int p = 0; p < 2; ++p) {
      __syncthreads();
      if (wr == p * 64) {
        #pragma unroll
        for (int j = 0; j < 4; ++j) {
          const int cl = wc + j * 16 + fr;
          const float bv = bias[col0 + cl];
          #pragma unroll
          for (int i = 0; i < 4; ++i)
            #pragma unroll
            for (int r = 0; r < 4; ++r)
              Ep[(i * 16 + quad * 4 + r) * 128 + cl] = acc[i][j][r] + bv;
        }
      }
      __syncthreads();
      #pragma unroll
      for (int k = 0; k < 8; ++k) {
        const int cell = tid + 256 * k;        // 0..2047
        const int ul = cell & 31;
        const int er = cell >> 5;              // 0..63
        const int row = row0 + p * 64 + er;
        const int unit = ub + ul;
        const float gi = Ep[er * 128 + ul];
        const float gf = Ep[er * 128 + 32 + ul];
        const float gc = Ep[er * 128 + 64 + ul];
        const float go = Ep[er * 128 + 96 + ul];
        const float cp = aux0[(size_t)row * NH + unit];
        const float cn = sigm(gf) * cp + sigm(gi) * tanhf(gc);
        const float hn = sigm(go) * tanhf(cn);
        const size_t hidx = (size_t)row * NH + unit;
        split(hn, &o1[hidx], &o2[hidx]);
        float2 hc; hc.x = hn; hc.y = cn;
        *(float2*)(out0 + 2 * hidx) = hc;
      }
    }
  }
}

// ================= weight / bias prep =================
__global__ void wconv(const float* __restrict__ src, int M0, int K0,
                      ushort* __restrict__ hi, ushort* __restrict__ lo,
                      int Mp, int Kp){
  int idx = blockIdx.x * blockDim.x + threadIdx.x;
  if (idx >= Mp * Kp) return;
  int r = idx / Kp, c = idx - r * Kp;
  float v = (r < M0 && c < K0) ? src[(size_t)r * K0 + c] : 0.f;
  split(v, &hi[idx], &lo[idx]);
}

// gate-permuted weight conversion: dst row r' <- src row g*128+u,
// r' = 128*(u>>5) + 32*g + (u&31)  <=>  y=r'>>7, g=(r'>>5)&3, u=32y+(r'&31)
__global__ void wconv_g(const float* __restrict__ src, int K0,
                        ushort* __restrict__ hi, ushort* __restrict__ lo, int Kp){
  int idx = blockIdx.x * blockDim.x + threadIdx.x;
  if (idx >= 512 * Kp) return;
  int rp = idx / Kp, c = idx - rp * Kp;
  int y = rp >> 7, g = (rp >> 5) & 3, u = (y << 5) | (rp & 31);
  float v = (c < K0) ? src[(size_t)(g * 128 + u) * K0 + c] : 0.f;
  split(v, &hi[idx], &lo[idx]);
}

__global__ void bias_pad(const float* __restrict__ s1, const float* __restrict__ s2,
                         int L, float* __restrict__ dst, int Lp){
  int idx = blockIdx.x * blockDim.x + threadIdx.x;
  if (idx >= Lp) return;
  float v = 0.f;
  if (idx < L) { v = s1[idx]; if (s2) v += s2[idx]; }
  dst[idx] = v;
}

__global__ void bias_g(const float* __restrict__ s1, const float* __restrict__ s2,
                       float* __restrict__ dst){
  int rp = blockIdx.x * blockDim.x + threadIdx.x;
  if (rp >= 512) return;
  int y = rp >> 7, g = (rp >> 5) & 3, u = (y << 5) | (rp & 31);
  int sr = g * 128 + u;
  dst[rp] = s1[sr] + s2[sr];
}

__global__ void fill_fwd(ushort* __restrict__ hi, ushort* __restrict__ lo){
  int idx = blockIdx.x * blockDim.x + threadIdx.x;
  if (idx >= 512 * 512) return;
  int c = idx >> 9, n = idx & 511;
  int k = c >> 1, m = (k * n) & 511;
  float th = (float)m * (6.283185307179586f / 512.0f);
  float s, co; sincosf(th, &s, &co);
  float v = (c & 1) ? -s : co;
  split(v, &hi[idx], &lo[idx]);
}

__global__ void fill_inv(ushort* __restrict__ hi, ushort* __restrict__ lo){
  int idx = blockIdx.x * blockDim.x + threadIdx.x;
  if (idx >= 512 * 544) return;
  int n = idx / 544, c = idx - n * 544;
  float v = 0.f;
  if (c < 512) {
    int k = c >> 1, m = (k * n) & 511;
    float th = (float)m * (6.283185307179586f / 512.0f);
    float s, co; sincosf(th, &s, &co);
    float w = (k == 0) ? (1.0f / 512.0f) : (2.0f / 512.0f);
    v = (c & 1) ? -w * s : w * co;
  } else if (c == 512) {
    v = ((n & 1) ? -1.0f : 1.0f) / 512.0f;
  }
  split(v, &hi[idx], &lo[idx]);
}

// ================= elementwise =================
__global__ void convert_x(const float* __restrict__ x,
                          ushort* __restrict__ hi, ushort* __restrict__ lo){
  int idx = blockIdx.x * blockDim.x + threadIdx.x;
  if (idx >= BN * 544) return;
  int r = idx / 544, c = idx - r * 544;
  float v = (c < 512) ? x[(size_t)r * 512 + c] : 0.f;
  split(v, &hi[idx], &lo[idx]);
}

// Nyquist: RI[n][512]=sum x*(-1)^i, RI[n][513]=0, mag bins 256..287
__global__ void nyq_kernel(const float* __restrict__ x, float* __restrict__ RI,
                           ushort* __restrict__ mhi, ushort* __restrict__ mlo){
  int row  = blockIdx.x * 4 + (threadIdx.x >> 6);
  int lane = threadIdx.x & 63;
  const float* xr = x + (size_t)row * 512;
  float s = 0.f;
  #pragma unroll
  for (int i = 0; i < 8; ++i) {
    int n = lane + 64 * i;
    float v = xr[n];
    s += (n & 1) ? -v : v;
  }
  #pragma unroll
  for (int off = 32; off >= 1; off >>= 1) s += __shfl_xor(s, off, 64);
  if (lane == 0) {
    RI[(size_t)row * 514 + 512] = s;
    RI[(size_t)row * 514 + 513] = 0.f;
  }
  if (lane < 32) {
    float mg = (lane == 0) ? sqrtf(fmaxf(s * s, EPSF)) : 0.f;
    size_t p = (size_t)row * 288 + 256 + lane;
    split(mg, &mhi[p], &mlo[p]);
  }
}

// in_state (2,BN,NH,2) f32 -> H hi/lo planes + C f32 (both layers)
__global__ void unpack_state(const float* __restrict__ st,
                             ushort* __restrict__ h1hi, ushort* __restrict__ h1lo,
                             float* __restrict__ c1,
                             ushort* __restrict__ h2hi, ushort* __restrict__ h2lo,
                             float* __restrict__ c2){
  int idx = blockIdx.x * blockDim.x + threadIdx.x;
  if (idx >= BN * NH) return;
  split(st[(size_t)idx * 2], &h1hi[idx], &h1lo[idx]);
  c1[idx] = st[(size_t)idx * 2 + 1];
  size_t off = (size_t)BN * NH * 2;
  split(st[off + (size_t)idx * 2], &h2hi[idx], &h2lo[idx]);
  c2[idx] = st[off + (size_t)idx * 2 + 1];
}

// LayerNorm over 256 -> ENCN hi/lo planes
__global__ void ln_kernel(const float* __restrict__ ENC,
                          const float* __restrict__ gamma,
                          const float* __restrict__ beta,
                          ushort* __restrict__ ohi, ushort* __restrict__ olo){
  int row = blockIdx.x;
  int t = threadIdx.x;   // 64
  const float* e = ENC + (size_t)row * NE;
  float v[4]; float s = 0.f;
  #pragma unroll
  for (int i = 0; i < 4; ++i) { v[i] = e[t + 64 * i]; s += v[i]; }
  #pragma unroll
  for (int off = 32; off >= 1; off >>= 1) s += __shfl_xor(s, off, 64);
  float mean = s * (1.0f / NE);
  float d[4]; float ss = 0.f;
  #pragma unroll
  for (int i = 0; i < 4; ++i) { d[i] = v[i] - mean; ss += d[i] * d[i]; }
  #pragma unroll
  for (int off = 32; off >= 1; off >>= 1) ss += __shfl_xor(ss, off, 64);
  float inv = 1.0f / sqrtf(ss * (1.0f / NE) + LNEPS);
  #pragma unroll
  for (int i = 0; i < 4; ++i) {
    int col = t + 64 * i;
    float o = d[i] * inv * gamma[col] + beta[col];
    size_t p = (size_t)row * NE + col;
    split(o, &ohi[p], &olo[p]);
  }
}

// ================= launch =================
extern "C" void kernel_launch(void* const* d_in, const int* in_sizes, int n_in,
                              void* d_out, int out_size, void* d_ws, size_t ws_size,
                              hipStream_t stream)
{
  const float* x       = (const float*)d_in[0];
  const float* st1     = (const float*)d_in[1];
  const float* st2     = (const float*)d_in[2];
  const float* s1_wih1 = (const float*)d_in[3];
  const float* s1_whh1 = (const float*)d_in[4];
  const float* s1_bih1 = (const float*)d_in[5];
  const float* s1_bhh1 = (const float*)d_in[6];
  const float* s1_wih2 = (const float*)d_in[7];
  const float* s1_whh2 = (const float*)d_in[8];
  const float* s1_bih2 = (const float*)d_in[9];
  const float* s1_bhh2 = (const float*)d_in[10];
  const float* s1_dw   = (const float*)d_in[11];
  const float* s1_db   = (const float*)d_in[12];
  const float* enc_w   = (const float*)d_in[13];
  const float* ln_g    = (const float*)d_in[14];
  const float* ln_b    = (const float*)d_in[15];
  const float* s2_wih1 = (const float*)d_in[16];
  const float* s2_whh1 = (const float*)d_in[17];
  const float* s2_bih1 = (const float*)d_in[18];
  const float* s2_bhh1 = (const float*)d_in[19];
  const float* s2_wih2 = (const float*)d_in[20];
  const float* s2_whh2 = (const float*)d_in[21];
  const float* s2_bih2 = (const float*)d_in[22];
  const float* s2_bhh2 = (const float*)d_in[23];
  const float* s2_dw   = (const float*)d_in[24];
  const float* s2_db   = (const float*)d_in[25];
  const float* dec_w   = (const float*)d_in[26];

  float* out_dec = (float*)d_out;
  float* out_st1 = out_dec + (size_t)BN * NFFT;
  float* out_st2 = out_st1 + (size_t)2 * BN * NH * 2;

  // ---- workspace ----
  char* base = (char*)d_ws;
  size_t off = 0;
  auto alloc = [&](size_t bytes) -> void* {
    off = (off + 255) & ~(size_t)255;
    void* p = base + off;
    off += bytes;
    return p;
  };
  ushort* fwdThi = (ushort*)alloc((size_t)512 * 512 * 2);
  ushort* fwdTlo = (ushort*)alloc((size_t)512 * 512 * 2);
  ushort* invThi = (ushort*)alloc((size_t)512 * 544 * 2);
  ushort* invTlo = (ushort*)alloc((size_t)512 * 544 * 2);
  ushort* XShi   = (ushort*)alloc((size_t)BN * 544 * 2);
  ushort* XSlo   = (ushort*)alloc((size_t)BN * 544 * 2);
  float*  RI     = (float*) alloc((size_t)BN * 514 * 4);
  float*  G      = (float*) alloc((size_t)BN * 512 * 4);  // Y1 planes region
  char*   R1     = (char*)  alloc((size_t)BN * NE * 4 * 2);
  ushort* h1hi   = (ushort*)alloc((size_t)BN * NH * 2);
  ushort* h1lo   = (ushort*)alloc((size_t)BN * NH * 2);
  ushort* h2hi   = (ushort*)alloc((size_t)BN * NH * 2);
  ushort* h2lo   = (ushort*)alloc((size_t)BN * NH * 2);
  ushort* h1nhi  = (ushort*)alloc((size_t)BN * NH * 2);
  ushort* h1nlo  = (ushort*)alloc((size_t)BN * NH * 2);
  ushort* h2nhi  = (ushort*)alloc((size_t)BN * NH * 2);
  ushort* h2nlo  = (ushort*)alloc((size_t)BN * NH * 2);
  float*  C1     = (float*) alloc((size_t)BN * NH * 4);
  float*  C2     = (float*) alloc((size_t)BN * NH * 4);
  ushort* w11hi = (ushort*)alloc((size_t)512*288*2); ushort* w11lo = (ushort*)alloc((size_t)512*288*2);
  ushort* wh1hi = (ushort*)alloc((size_t)512*128*2); ushort* wh1lo = (ushort*)alloc((size_t)512*128*2);
  ushort* w12hi = (ushort*)alloc((size_t)512*128*2); ushort* w12lo = (ushort*)alloc((size_t)512*128*2);
  ushort* wh2hi = (ushort*)alloc((size_t)512*128*2); ushort* wh2lo = (ushort*)alloc((size_t)512*128*2);
  ushort* dw1hi = (ushort*)alloc((size_t)384*128*2); ushort* dw1lo = (ushort*)alloc((size_t)384*128*2);
  ushort* encwhi= (ushort*)alloc((size_t)256*512*2); ushort* encwlo= (ushort*)alloc((size_t)256*512*2);
  ushort* w21hi = (ushort*)alloc((size_t)512*256*2); ushort* w21lo = (ushort*)alloc((size_t)512*256*2);
  ushort* wh3hi = (ushort*)alloc((size_t)512*128*2); ushort* wh3lo = (ushort*)alloc((size_t)512*128*2);
  ushort* w22hi = (ushort*)alloc((size_t)512*128*2); ushort* w22lo = (ushort*)alloc((size_t)512*128*2);
  ushort* wh4hi = (ushort*)alloc((size_t)512*128*2); ushort* wh4lo = (ushort*)alloc((size_t)512*128*2);
  ushort* dw2hi = (ushort*)alloc((size_t)256*128*2); ushort* dw2lo = (ushort*)alloc((size_t)256*128*2);
  ushort* decwhi= (ushort*)alloc((size_t)512*256*2); ushort* decwlo= (ushort*)alloc((size_t)512*256*2);
  float* bg1 = (float*)alloc(512*4); float* bg2 = (float*)alloc(512*4);
  float* bm1 = (float*)alloc(384*4);
  float* bg3 = (float*)alloc(512*4); float* bg4 = (float*)alloc(512*4);
  float* bm2 = (float*)alloc(256*4);
  (void)ws_size; (void)in_sizes; (void)n_in; (void)out_size;

  // region overlays
  ushort* maghi  = (ushort*)R1;                              // [BN][288]
  ushort* maglo  = (ushort*)(R1 + (size_t)BN * 288 * 2);
  float*  ENC    = (float*)R1;                               // [BN][256] (MAG dead)
  ushort* ENCNhi = (ushort*)(R1 + (size_t)BN * NE * 4);      // [BN][256]
  ushort* ENCNlo = (ushort*)(R1 + (size_t)BN * NE * 4 + (size_t)BN * NE * 2);
  ushort* Dhi    = ENCNhi;                                   // dec-in planes
  ushort* Dlo    = ENCNlo;
  ushort* Y1hi   = (ushort*)G;                               // [BN][512]
  ushort* Y1lo   = (ushort*)G + (size_t)BN * 512;

  const dim3 blk(256);
  auto ceilb = [](long n){ return (int)((n + 255) / 256); };

  // ---- prep ----
  fill_fwd<<<ceilb((long)512*512), blk, 0, stream>>>(fwdThi, fwdTlo);
  fill_inv<<<ceilb((long)512*544), blk, 0, stream>>>(invThi, invTlo);
  wconv_g<<<ceilb((long)512*288), blk, 0, stream>>>(s1_wih1, 257, w11hi, w11lo, 288);
  wconv_g<<<ceilb((long)512*128), blk, 0, stream>>>(s1_whh1, 128, wh1hi, wh1lo, 128);
  wconv_g<<<ceilb((long)512*128), blk, 0, stream>>>(s1_wih2, 128, w12hi, w12lo, 128);
  wconv_g<<<ceilb((long)512*128), blk, 0, stream>>>(s1_whh2, 128, wh2hi, wh2lo, 128);
  wconv<<<ceilb((long)384*128), blk, 0, stream>>>(s1_dw,   257, 128, dw1hi, dw1lo, 384, 128);
  wconv<<<ceilb((long)256*512), blk, 0, stream>>>(enc_w,   256, 512, encwhi, encwlo, 256, 512);
  wconv_g<<<ceilb((long)512*256), blk, 0, stream>>>(s2_wih1, 256, w21hi, w21lo, 256);
  wconv_g<<<ceilb((long)512*128), blk, 0, stream>>>(s2_whh1, 128, wh3hi, wh3lo, 128);
  wconv_g<<<ceilb((long)512*128), blk, 0, stream>>>(s2_wih2, 128, w22hi, w22lo, 128);
  wconv_g<<<ceilb((long)512*128), blk, 0, stream>>>(s2_whh2, 128, wh4hi, wh4lo, 128);
  wconv<<<ceilb((long)256*128), blk, 0, stream>>>(s2_dw,   256, 128, dw2hi, dw2lo, 256, 128);
  wconv<<<ceilb((long)512*256), blk, 0, stream>>>(dec_w,   512, 256, decwhi, decwlo, 512, 256);
  bias_g<<<2, blk, 0, stream>>>(s1_bih1, s1_bhh1, bg1);
  bias_g<<<2, blk, 0, stream>>>(s1_bih2, s1_bhh2, bg2);
  bias_pad<<<2, blk, 0, stream>>>(s1_db,   nullptr, 257, bm1, 384);
  bias_g<<<2, blk, 0, stream>>>(s2_bih1, s2_bhh1, bg3);
  bias_g<<<2, blk, 0, stream>>>(s2_bih2, s2_bhh2, bg4);
  bias_pad<<<1, blk, 0, stream>>>(s2_db,   nullptr, 256, bm2, 256);

  convert_x<<<ceilb((long)BN*544), blk, 0, stream>>>(x, XShi, XSlo);
  unpack_state<<<ceilb((long)BN*NH), blk, 0, stream>>>(st1, h1hi, h1lo, C1, h2hi, h2lo, C2);

  // ---- rfft (+fused magphase) + Nyquist ----
  mfma_gemm<M_RFFT><<<dim3(128,4), blk, 0, stream>>>(XShi, XSlo, 544, 512,
      fwdThi, fwdTlo, nullptr, nullptr, 0, 0, nullptr, nullptr,
      nullptr, RI, nullptr, nullptr, 514,
      nullptr, nullptr, nullptr, nullptr, maghi, maglo);
  nyq_kernel<<<BN/4, blk, 0, stream>>>(x, RI, maghi, maglo);

  // ---- sep block 1 (fused LSTM epilogues) ----
  mfma_gemm<M_LSTM><<<dim3(128,4), blk, 0, stream>>>(maghi, maglo, 288, 288,
      w11hi, w11lo, h1hi, h1lo, 128, 128, wh1hi, wh1lo,
      bg1, nullptr, nullptr, nullptr, 0,
      C1, nullptr, nullptr, out_st1, h1nhi, h1nlo);
  mfma_gemm<M_LSTM><<<dim3(128,4), blk, 0, stream>>>(h1nhi, h1nlo, 128, 128,
      w12hi, w12lo, h2hi, h2lo, 128, 128, wh2hi, wh2lo,
      bg2, nullptr, nullptr, nullptr, 0,
      C2, nullptr, nullptr, out_st1 + (size_t)BN*NH*2, h2nhi, h2nlo);
  // ---- mask1 + fused est_build -> XS planes ----
  mfma_gemm<M_EST><<<dim3(128,3), blk, 0, stream>>>(h2nhi, h2nlo, 128, 128,
      dw1hi, dw1lo, nullptr, nullptr, 0, 0, nullptr, nullptr,
      bm1, nullptr, nullptr, nullptr, 0,
      RI, maghi, maglo, nullptr, XShi, XSlo);

  // ---- irfft -> Y1 planes ----
  mfma_gemm<M_PLANES><<<dim3(128,4), blk, 0, stream>>>(XShi, XSlo, 544, 544,
      invThi, invTlo, nullptr, nullptr, 0, 0, nullptr, nullptr,
      nullptr, nullptr, Y1hi, Y1lo, 512,
      nullptr, nullptr, nullptr, nullptr, nullptr, nullptr);

  // ---- encoder + LN ----
  mfma_gemm<M_F32><<<dim3(128,2), blk, 0, stream>>>(Y1hi, Y1lo, 512, 512,
      encwhi, encwlo, nullptr, nullptr, 0, 0, nullptr, nullptr,
      nullptr, ENC, nullptr, nullptr, 256,
      nullptr, nullptr, nullptr, nullptr, nullptr, nullptr);
  ln_kernel<<<BN, 64, 0, stream>>>(ENC, ln_g, ln_b, ENCNhi, ENCNlo);

  // ---- sep block 2 ----
  unpack_state<<<ceilb((long)BN*NH), blk, 0, stream>>>(st2, h1hi, h1lo, C1, h2hi, h2lo, C2);
  mfma_gemm<M_LSTM><<<dim3(128,4), blk, 0, stream>>>(ENCNhi, ENCNlo, 256, 256,
      w21hi, w21lo, h1hi, h1lo, 128, 128, wh3hi, wh3lo,
      bg3, nullptr, nullptr, nullptr, 0,
      C1, nullptr, nullptr, out_st2, h1nhi, h1nlo);
  mfma_gemm<M_LSTM><<<dim3(128,4), blk, 0, stream>>>(h1nhi, h1nlo, 128, 128,
      w22hi, w22lo, h2hi, h2lo, 128, 128, wh4hi, wh4lo,
      bg4, nullptr, nullptr, nullptr, 0,
      C2, nullptr, nullptr, out_st2 + (size_t)BN*NH*2, h2nhi, h2nlo);
  // ---- mask2 + fused dec_in -> D planes ----
  mfma_gemm<M_DEC><<<dim3(128,2), blk, 0, stream>>>(h2nhi, h2nlo, 128, 128,
      dw2hi, dw2lo, nullptr, nullptr, 0, 0, nullptr, nullptr,
      bm2, nullptr, nullptr, nullptr, 0,
      ENC, nullptr, nullptr, nullptr, Dhi, Dlo);

  // ---- decoder ----
  mfma_gemm<M_F32><<<dim3(128,4), blk, 0, stream>>>(Dhi, Dlo, 256, 256,
      decwhi, decwlo, nullptr, nullptr, 0, 0, nullptr, nullptr,
      nullptr, out_dec, nullptr, nullptr, 512,
      nullptr, nullptr, nullptr, nullptr, nullptr, nullptr);
}

// Round 5
// 425.538 us; speedup vs baseline: 1.1139x; 1.0079x over previous
//
#include <hip/hip_runtime.h>
#include <hip/hip_bf16.h>
#include <math.h>

static constexpr int BN   = 16384;
static constexpr int NFFT = 512;
static constexpr int NBIN = 257;
static constexpr int NH   = 128;
static constexpr int NE   = 256;
static constexpr float EPSF  = 1.1920929e-07f;
static constexpr float LNEPS = 1e-07f;

using short8  = __attribute__((ext_vector_type(8))) short;
using float4v = __attribute__((ext_vector_type(4))) float;

__device__ __forceinline__ float sigm(float x){ return 1.0f/(1.0f+expf(-x)); }
__device__ __forceinline__ ushort f2b(float v){
  __hip_bfloat16 b = __float2bfloat16(v);
  return *reinterpret_cast<ushort*>(&b);
}
__device__ __forceinline__ float b2f(ushort u){
  __hip_bfloat16 b = *reinterpret_cast<__hip_bfloat16*>(&u);
  return __bfloat162float(b);
}
__device__ __forceinline__ void split(float v, ushort* hi, ushort* lo){
  ushort h = f2b(v);
  *hi = h;
  *lo = f2b(v - b2f(h));
}

__device__ __forceinline__ void gload16(const ushort* g, ushort* l){
  __builtin_amdgcn_global_load_lds(
      (const __attribute__((address_space(1))) unsigned int*)g,
      (__attribute__((address_space(3))) unsigned int*)l,
      16, 0, 0);
}

// epilogue modes
enum { M_F32 = 0, M_PLANES = 1, M_LSTM = 2, M_EST = 3, M_DEC = 4, M_RFFT = 5 };

// ================= MFMA bf16x2 NT GEMM, BM=64 / BN=128 =================
// C[row][col] = sum_k A[row][k]*B[col][k] (+ optional phase2 A2/B2)
// Tile 64x128, 4 waves of 32x64 (acc[2][4]). Single-buffered LDS 24 KB
// (A [64][64] + B [128][64] ushorts) -> 4+ blocks/CU at grid 1024 (m97-style
// multi-block latency hiding). XOR swizzle folded into per-lane global src
// for global_load_lds (linear dest); read-side XOR (r&7)<<4.
// MODE_LSTM expects gate-PERMUTED weights/bias: col' = 128*(u>>5)+32*g+(u&31).
template<int MODE>
__global__ __launch_bounds__(256)
void mfma_gemm(const ushort* __restrict__ Ahi, const ushort* __restrict__ Alo,
               int lda, int K,
               const ushort* __restrict__ Bhi, const ushort* __restrict__ Blo,
               const ushort* __restrict__ A2hi, const ushort* __restrict__ A2lo,
               int lda2, int K2,
               const ushort* __restrict__ B2hi, const ushort* __restrict__ B2lo,
               const float* __restrict__ bias,
               float* __restrict__ C, ushort* __restrict__ Chi,
               ushort* __restrict__ Clo, int ldc,
               const float* __restrict__ aux0,   // LSTM: c_in | EST: RI | DEC: ENC
               const ushort* __restrict__ aux1,  // EST: maghi
               const ushort* __restrict__ aux2,  // EST: maglo
               float* __restrict__ out0,         // LSTM: out_state (h,c pairs)
               ushort* __restrict__ o1,          // LSTM: h_hi | EST: XShi | DEC: Dhi | RFFT: maghi
               ushort* __restrict__ o2)          // lo counterparts
{
  // staging: A segs 0..7 at [0..4096), B segs 0..15 at [4096..12288) ushorts
  // LSTM epilogue overlays 64x128 f32 = 16384 ushorts
  constexpr int LDSW = (MODE == M_LSTM) ? 16384 : 12288;
  __shared__ ushort smem[LDSW];
  const int tid  = threadIdx.x;
  const int row0 = blockIdx.x * 64;
  const int col0 = blockIdx.y * 128;
  const int lane = tid & 63;
  const int wv   = tid >> 6;
  const int wr   = (wv >> 1) * 32;   // 0 / 32
  const int wc   = (wv & 1) * 64;    // 0 / 64
  const int fr   = lane & 15;
  const int quad = lane >> 4;

  const int lrow   = lane >> 3;        // 0..7
  const int pslot  = lane & 7;
  const int lslot  = pslot ^ lrow;     // logical slot this lane fetches
  const int kchunk = (lslot & 3) * 8;
  const bool isHi  = (lslot < 4);

  float4v acc[2][4];
  #pragma unroll
  for (int i = 0; i < 2; ++i)
    #pragma unroll
    for (int j = 0; j < 4; ++j)
      acc[i][j] = float4v{0.f, 0.f, 0.f, 0.f};

  const int nt0 = K / 32;
  const int nt1 = A2hi ? (K2 / 32) : 0;
  const int nt  = nt0 + nt1;

  const ushort* ap0 = isHi ? Ahi : Alo;
  const ushort* bp0 = isHi ? Bhi : Blo;
  const ushort* ap1 = isHi ? A2hi : A2lo;
  const ushort* bp1 = isHi ? B2hi : B2lo;
  size_t a0[2], a1[2], b0[4], b1[4];
  #pragma unroll
  for (int s = 0; s < 2; ++s) {
    const int r = (wv * 2 + s) * 8 + lrow;          // 0..63
    a0[s] = (size_t)(row0 + r) * lda  + kchunk;
    a1[s] = (size_t)(row0 + r) * lda2 + kchunk;
  }
  #pragma unroll
  for (int s = 0; s < 4; ++s) {
    const int r = (wv * 4 + s) * 8 + lrow;          // 0..127
    b0[s] = (size_t)(col0 + r) * K  + kchunk;
    b1[s] = (size_t)(col0 + r) * K2 + kchunk;
  }

  #pragma unroll 1
  for (int t = 0; t < nt; ++t) {
    // ---- stage 64x32 A + 128x32 B (hi/lo interleaved via lslot) ----
    if (t < nt0) {
      #pragma unroll
      for (int s = 0; s < 2; ++s)
        gload16(ap0 + a0[s] + (size_t)t * 32, &smem[(wv * 2 + s) * 512]);
      #pragma unroll
      for (int s = 0; s < 4; ++s)
        gload16(bp0 + b0[s] + (size_t)t * 32, &smem[4096 + (wv * 4 + s) * 512]);
    } else {
      const int kt = t - nt0;
      #pragma unroll
      for (int s = 0; s < 2; ++s)
        gload16(ap1 + a1[s] + (size_t)kt * 32, &smem[(wv * 2 + s) * 512]);
      #pragma unroll
      for (int s = 0; s < 4; ++s)
        gload16(bp1 + b1[s] + (size_t)kt * 32, &smem[4096 + (wv * 4 + s) * 512]);
    }
    asm volatile("s_waitcnt vmcnt(0)" ::: "memory");
    __syncthreads();

    // ---- fragments (swizzled reads) ----
    const char* Ab = (const char*)smem;
    const char* Bb = (const char*)(smem + 4096);
    short8 ah[2], al[2], bh[4], bl[4];
    #pragma unroll
    for (int i = 0; i < 2; ++i) {
      const int ra  = wr + i * 16 + fr;
      const int swa = (ra & 7) << 4;
      ah[i] = *(const short8*)(Ab + ra * 128 + ((quad << 4) ^ swa));
      al[i] = *(const short8*)(Ab + ra * 128 + ((64 | (quad << 4)) ^ swa));
    }
    #pragma unroll
    for (int j = 0; j < 4; ++j) {
      const int rb  = wc + j * 16 + fr;
      const int swb = (rb & 7) << 4;
      bh[j] = *(const short8*)(Bb + rb * 128 + ((quad << 4) ^ swb));
      bl[j] = *(const short8*)(Bb + rb * 128 + ((64 | (quad << 4)) ^ swb));
    }
    #pragma unroll
    for (int i = 0; i < 2; ++i)
      #pragma unroll
      for (int j = 0; j < 4; ++j) {
        acc[i][j] = __builtin_amdgcn_mfma_f32_16x16x32_bf16(ah[i], bh[j], acc[i][j], 0, 0, 0);
        acc[i][j] = __builtin_amdgcn_mfma_f32_16x16x32_bf16(ah[i], bl[j], acc[i][j], 0, 0, 0);
        acc[i][j] = __builtin_amdgcn_mfma_f32_16x16x32_bf16(al[i], bh[j], acc[i][j], 0, 0, 0);
      }
    __syncthreads();
  }

  // ---- epilogues; C/D layout: col=lane&15 group, row=quad*4+reg ----
  if constexpr (MODE == M_F32) {
    #pragma unroll
    for (int j = 0; j < 4; ++j) {
      const int colb = col0 + wc + j * 16 + fr;
      const float bv = bias ? bias[colb] : 0.f;
      #pragma unroll
      for (int i = 0; i < 2; ++i)
        #pragma unroll
        for (int r = 0; r < 4; ++r) {
          const int row = row0 + wr + i * 16 + quad * 4 + r;
          C[(size_t)row * ldc + colb] = acc[i][j][r] + bv;
        }
    }
  } else if constexpr (MODE == M_PLANES) {
    #pragma unroll
    for (int j = 0; j < 4; ++j) {
      const int colb = col0 + wc + j * 16 + fr;
      #pragma unroll
      for (int i = 0; i < 2; ++i)
        #pragma unroll
        for (int r = 0; r < 4; ++r) {
          const int row = row0 + wr + i * 16 + quad * 4 + r;
          const size_t idx = (size_t)row * ldc + colb;
          split(acc[i][j][r], &Chi[idx], &Clo[idx]);
        }
    }
  } else if constexpr (MODE == M_RFFT) {
    #pragma unroll
    for (int j = 0; j < 4; ++j) {
      const int colb = col0 + wc + j * 16 + fr;
      #pragma unroll
      for (int i = 0; i < 2; ++i)
        #pragma unroll
        for (int r = 0; r < 4; ++r) {
          const int row = row0 + wr + i * 16 + quad * 4 + r;
          const float v = acc[i][j][r];
          C[(size_t)row * ldc + colb] = v;
          const float w = __shfl_xor(v, 1, 64);
          if (!(lane & 1)) {
            const int bin = colb >> 1;
            const float mg = sqrtf(fmaxf(v * v + w * w, EPSF));
            split(mg, &o1[(size_t)row * 288 + bin], &o2[(size_t)row * 288 + bin]);
          }
        }
    }
  } else if constexpr (MODE == M_EST) {
    #pragma unroll
    for (int j = 0; j < 4; ++j) {
      const int colg = col0 + wc + j * 16 + fr;   // bin index
      const float bv = bias[colg];
      #pragma unroll
      for (int i = 0; i < 2; ++i)
        #pragma unroll
        for (int r = 0; r < 4; ++r) {
          const int row = row0 + wr + i * 16 + quad * 4 + r;
          const size_t pp = (size_t)row * 544 + 2 * colg;
          if (colg < NBIN) {
            const float m   = sigm(acc[i][j][r] + bv);
            const float mag = b2f(aux1[(size_t)row * 288 + colg]) +
                              b2f(aux2[(size_t)row * 288 + colg]);
            const float e   = m * mag;
            const float rr  = aux0[(size_t)row * 514 + 2 * colg];
            const float im  = aux0[(size_t)row * 514 + 2 * colg + 1];
            const float re = rr + EPSF, ie = im + EPSF;
            const float hyp = fmaxf(sqrtf(re * re + ie * ie), 1e-35f);
            const float cr = e * re / hyp, ci = e * ie / hyp;
            split(cr, &o1[pp], &o2[pp]);
            split(ci, &o1[pp + 1], &o2[pp + 1]);
          } else if (colg < 272) {
            o1[pp] = 0; o1[pp + 1] = 0;
            o2[pp] = 0; o2[pp + 1] = 0;
          }
        }
    }
  } else if constexpr (MODE == M_DEC) {
    #pragma unroll
    for (int j = 0; j < 4; ++j) {
      const int colg = col0 + wc + j * 16 + fr;
      const float bv = bias[colg];
      #pragma unroll
      for (int i = 0; i < 2; ++i)
        #pragma unroll
        for (int r = 0; r < 4; ++r) {
          const int row = row0 + wr + i * 16 + quad * 4 + r;
          const size_t idx = (size_t)row * NE + colg;
          const float v = sigm(acc[i][j][r] + bv) * aux0[idx];
          split(v, &o1[idx], &o2[idx]);
        }
    }
  } else {
    // M_LSTM: block's 128 cols = units ub..ub+31, gates 0..3 (permuted)
    float* Ep = (float*)smem;   // 64 rows x 128 gate-cols f32 = 32 KB
    const int ub = blockIdx.y << 5;
    #pragma unroll
    for (int j = 0; j < 4; ++j) {
      const int cl = wc + j * 16 + fr;
      const float bv = bias[col0 + cl];
      #pragma unroll
      for (int i = 0; i < 2; ++i)
        #pragma unroll
        for (int r = 0; r < 4; ++r)
          Ep[(wr + i * 16 + quad * 4 + r) * 128 + cl] = acc[i][j][r] + bv;
    }
    __syncthreads();
    #pragma unroll
    for (int k = 0; k < 8; ++k) {
      const int cell = tid + 256 * k;        // 0..2047
      const int ul = cell & 31;
      const int er = cell >> 5;              // 0..63
      const int row = row0 + er;
      const int unit = ub + ul;
      const float gi = Ep[er * 128 + ul];
      const float gf = Ep[er * 128 + 32 + ul];
      const float gc = Ep[er * 128 + 64 + ul];
      const float go = Ep[er * 128 + 96 + ul];
      const float cp = aux0[(size_t)row * NH + unit];
      const float cn = sigm(gf) * cp + sigm(gi) * tanhf(gc);
      const float hn = sigm(go) * tanhf(cn);
      const size_t hidx = (size_t)row * NH + unit;
      split(hn, &o1[hidx], &o2[hidx]);
      float2 hc; hc.x = hn; hc.y = cn;
      *(float2*)(out0 + 2 * hidx) = hc;
    }
  }
}

// ================= weight / bias prep =================
__global__ void wconv(const float* __restrict__ src, int M0, int K0,
                      ushort* __restrict__ hi, ushort* __restrict__ lo,
                      int Mp, int Kp){
  int idx = blockIdx.x * blockDim.x + threadIdx.x;
  if (idx >= Mp * Kp) return;
  int r = idx / Kp, c = idx - r * Kp;
  float v = (r < M0 && c < K0) ? src[(size_t)r * K0 + c] : 0.f;
  split(v, &hi[idx], &lo[idx]);
}

// gate-permuted weight conversion: dst row r' <- src row g*128+u,
// r' = 128*(u>>5) + 32*g + (u&31)  <=>  y=r'>>7, g=(r'>>5)&3, u=32y+(r'&31)
__global__ void wconv_g(const float* __restrict__ src, int K0,
                        ushort* __restrict__ hi, ushort* __restrict__ lo, int Kp){
  int idx = blockIdx.x * blockDim.x + threadIdx.x;
  if (idx >= 512 * Kp) return;
  int rp = idx / Kp, c = idx - rp * Kp;
  int y = rp >> 7, g = (rp >> 5) & 3, u = (y << 5) | (rp & 31);
  float v = (c < K0) ? src[(size_t)(g * 128 + u) * K0 + c] : 0.f;
  split(v, &hi[idx], &lo[idx]);
}

__global__ void bias_pad(const float* __restrict__ s1, const float* __restrict__ s2,
                         int L, float* __restrict__ dst, int Lp){
  int idx = blockIdx.x * blockDim.x + threadIdx.x;
  if (idx >= Lp) return;
  float v = 0.f;
  if (idx < L) { v = s1[idx]; if (s2) v += s2[idx]; }
  dst[idx] = v;
}

__global__ void bias_g(const float* __restrict__ s1, const float* __restrict__ s2,
                       float* __restrict__ dst){
  int rp = blockIdx.x * blockDim.x + threadIdx.x;
  if (rp >= 512) return;
  int y = rp >> 7, g = (rp >> 5) & 3, u = (y << 5) | (rp & 31);
  int sr = g * 128 + u;
  dst[rp] = s1[sr] + s2[sr];
}

__global__ void fill_fwd(ushort* __restrict__ hi, ushort* __restrict__ lo){
  int idx = blockIdx.x * blockDim.x + threadIdx.x;
  if (idx >= 512 * 512) return;
  int c = idx >> 9, n = idx & 511;
  int k = c >> 1, m = (k * n) & 511;
  float th = (float)m * (6.283185307179586f / 512.0f);
  float s, co; sincosf(th, &s, &co);
  float v = (c & 1) ? -s : co;
  split(v, &hi[idx], &lo[idx]);
}

__global__ void fill_inv(ushort* __restrict__ hi, ushort* __restrict__ lo){
  int idx = blockIdx.x * blockDim.x + threadIdx.x;
  if (idx >= 512 * 544) return;
  int n = idx / 544, c = idx - n * 544;
  float v = 0.f;
  if (c < 512) {
    int k = c >> 1, m = (k * n) & 511;
    float th = (float)m * (6.283185307179586f / 512.0f);
    float s, co; sincosf(th, &s, &co);
    float w = (k == 0) ? (1.0f / 512.0f) : (2.0f / 512.0f);
    v = (c & 1) ? -w * s : w * co;
  } else if (c == 512) {
    v = ((n & 1) ? -1.0f : 1.0f) / 512.0f;
  }
  split(v, &hi[idx], &lo[idx]);
}

// ================= elementwise =================
__global__ void convert_x(const float* __restrict__ x,
                          ushort* __restrict__ hi, ushort* __restrict__ lo){
  int idx = blockIdx.x * blockDim.x + threadIdx.x;
  if (idx >= BN * 544) return;
  int r = idx / 544, c = idx - r * 544;
  float v = (c < 512) ? x[(size_t)r * 512 + c] : 0.f;
  split(v, &hi[idx], &lo[idx]);
}

// Nyquist: RI[n][512]=sum x*(-1)^i, RI[n][513]=0, mag bins 256..287
__global__ void nyq_kernel(const float* __restrict__ x, float* __restrict__ RI,
                           ushort* __restrict__ mhi, ushort* __restrict__ mlo){
  int row  = blockIdx.x * 4 + (threadIdx.x >> 6);
  int lane = threadIdx.x & 63;
  const float* xr = x + (size_t)row * 512;
  float s = 0.f;
  #pragma unroll
  for (int i = 0; i < 8; ++i) {
    int n = lane + 64 * i;
    float v = xr[n];
    s += (n & 1) ? -v : v;
  }
  #pragma unroll
  for (int off = 32; off >= 1; off >>= 1) s += __shfl_xor(s, off, 64);
  if (lane == 0) {
    RI[(size_t)row * 514 + 512] = s;
    RI[(size_t)row * 514 + 513] = 0.f;
  }
  if (lane < 32) {
    float mg = (lane == 0) ? sqrtf(fmaxf(s * s, EPSF)) : 0.f;
    size_t p = (size_t)row * 288 + 256 + lane;
    split(mg, &mhi[p], &mlo[p]);
  }
}

// in_state (2,BN,NH,2) f32 -> H hi/lo planes + C f32 (both layers)
__global__ void unpack_state(const float* __restrict__ st,
                             ushort* __restrict__ h1hi, ushort* __restrict__ h1lo,
                             float* __restrict__ c1,
                             ushort* __restrict__ h2hi, ushort* __restrict__ h2lo,
                             float* __restrict__ c2){
  int idx = blockIdx.x * blockDim.x + threadIdx.x;
  if (idx >= BN * NH) return;
  split(st[(size_t)idx * 2], &h1hi[idx], &h1lo[idx]);
  c1[idx] = st[(size_t)idx * 2 + 1];
  size_t off = (size_t)BN * NH * 2;
  split(st[off + (size_t)idx * 2], &h2hi[idx], &h2lo[idx]);
  c2[idx] = st[off + (size_t)idx * 2 + 1];
}

// LayerNorm over 256 -> ENCN hi/lo planes
__global__ void ln_kernel(const float* __restrict__ ENC,
                          const float* __restrict__ gamma,
                          const float* __restrict__ beta,
                          ushort* __restrict__ ohi, ushort* __restrict__ olo){
  int row = blockIdx.x;
  int t = threadIdx.x;   // 64
  const float* e = ENC + (size_t)row * NE;
  float v[4]; float s = 0.f;
  #pragma unroll
  for (int i = 0; i < 4; ++i) { v[i] = e[t + 64 * i]; s += v[i]; }
  #pragma unroll
  for (int off = 32; off >= 1; off >>= 1) s += __shfl_xor(s, off, 64);
  float mean = s * (1.0f / NE);
  float d[4]; float ss = 0.f;
  #pragma unroll
  for (int i = 0; i < 4; ++i) { d[i] = v[i] - mean; ss += d[i] * d[i]; }
  #pragma unroll
  for (int off = 32; off >= 1; off >>= 1) ss += __shfl_xor(ss, off, 64);
  float inv = 1.0f / sqrtf(ss * (1.0f / NE) + LNEPS);
  #pragma unroll
  for (int i = 0; i < 4; ++i) {
    int col = t + 64 * i;
    float o = d[i] * inv * gamma[col] + beta[col];
    size_t p = (size_t)row * NE + col;
    split(o, &ohi[p], &olo[p]);
  }
}

// ================= launch =================
extern "C" void kernel_launch(void* const* d_in, const int* in_sizes, int n_in,
                              void* d_out, int out_size, void* d_ws, size_t ws_size,
                              hipStream_t stream)
{
  const float* x       = (const float*)d_in[0];
  const float* st1     = (const float*)d_in[1];
  const float* st2     = (const float*)d_in[2];
  const float* s1_wih1 = (const float*)d_in[3];
  const float* s1_whh1 = (const float*)d_in[4];
  const float* s1_bih1 = (const float*)d_in[5];
  const float* s1_bhh1 = (const float*)d_in[6];
  const float* s1_wih2 = (const float*)d_in[7];
  const float* s1_whh2 = (const float*)d_in[8];
  const float* s1_bih2 = (const float*)d_in[9];
  const float* s1_bhh2 = (const float*)d_in[10];
  const float* s1_dw   = (const float*)d_in[11];
  const float* s1_db   = (const float*)d_in[12];
  const float* enc_w   = (const float*)d_in[13];
  const float* ln_g    = (const float*)d_in[14];
  const float* ln_b    = (const float*)d_in[15];
  const float* s2_wih1 = (const float*)d_in[16];
  const float* s2_whh1 = (const float*)d_in[17];
  const float* s2_bih1 = (const float*)d_in[18];
  const float* s2_bhh1 = (const float*)d_in[19];
  const float* s2_wih2 = (const float*)d_in[20];
  const float* s2_whh2 = (const float*)d_in[21];
  const float* s2_bih2 = (const float*)d_in[22];
  const float* s2_bhh2 = (const float*)d_in[23];
  const float* s2_dw   = (const float*)d_in[24];
  const float* s2_db   = (const float*)d_in[25];
  const float* dec_w   = (const float*)d_in[26];

  float* out_dec = (float*)d_out;
  float* out_st1 = out_dec + (size_t)BN * NFFT;
  float* out_st2 = out_st1 + (size_t)2 * BN * NH * 2;

  // ---- workspace ----
  char* base = (char*)d_ws;
  size_t off = 0;
  auto alloc = [&](size_t bytes) -> void* {
    off = (off + 255) & ~(size_t)255;
    void* p = base + off;
    off += bytes;
    return p;
  };
  ushort* fwdThi = (ushort*)alloc((size_t)512 * 512 * 2);
  ushort* fwdTlo = (ushort*)alloc((size_t)512 * 512 * 2);
  ushort* invThi = (ushort*)alloc((size_t)512 * 544 * 2);
  ushort* invTlo = (ushort*)alloc((size_t)512 * 544 * 2);
  ushort* XShi   = (ushort*)alloc((size_t)BN * 544 * 2);
  ushort* XSlo   = (ushort*)alloc((size_t)BN * 544 * 2);
  float*  RI     = (float*) alloc((size_t)BN * 514 * 4);
  float*  G      = (float*) alloc((size_t)BN * 512 * 4);  // Y1 planes region
  char*   R1     = (char*)  alloc((size_t)BN * NE * 4 * 2);
  ushort* h1hi   = (ushort*)alloc((size_t)BN * NH * 2);
  ushort* h1lo   = (ushort*)alloc((size_t)BN * NH * 2);
  ushort* h2hi   = (ushort*)alloc((size_t)BN * NH * 2);
  ushort* h2lo   = (ushort*)alloc((size_t)BN * NH * 2);
  ushort* h1nhi  = (ushort*)alloc((size_t)BN * NH * 2);
  ushort* h1nlo  = (ushort*)alloc((size_t)BN * NH * 2);
  ushort* h2nhi  = (ushort*)alloc((size_t)BN * NH * 2);
  ushort* h2nlo  = (ushort*)alloc((size_t)BN * NH * 2);
  float*  C1     = (float*) alloc((size_t)BN * NH * 4);
  float*  C2     = (float*) alloc((size_t)BN * NH * 4);
  ushort* w11hi = (ushort*)alloc((size_t)512*288*2); ushort* w11lo = (ushort*)alloc((size_t)512*288*2);
  ushort* wh1hi = (ushort*)alloc((size_t)512*128*2); ushort* wh1lo = (ushort*)alloc((size_t)512*128*2);
  ushort* w12hi = (ushort*)alloc((size_t)512*128*2); ushort* w12lo = (ushort*)alloc((size_t)512*128*2);
  ushort* wh2hi = (ushort*)alloc((size_t)512*128*2); ushort* wh2lo = (ushort*)alloc((size_t)512*128*2);
  ushort* dw1hi = (ushort*)alloc((size_t)384*128*2); ushort* dw1lo = (ushort*)alloc((size_t)384*128*2);
  ushort* encwhi= (ushort*)alloc((size_t)256*512*2); ushort* encwlo= (ushort*)alloc((size_t)256*512*2);
  ushort* w21hi = (ushort*)alloc((size_t)512*256*2); ushort* w21lo = (ushort*)alloc((size_t)512*256*2);
  ushort* wh3hi = (ushort*)alloc((size_t)512*128*2); ushort* wh3lo = (ushort*)alloc((size_t)512*128*2);
  ushort* w22hi = (ushort*)alloc((size_t)512*128*2); ushort* w22lo = (ushort*)alloc((size_t)512*128*2);
  ushort* wh4hi = (ushort*)alloc((size_t)512*128*2); ushort* wh4lo = (ushort*)alloc((size_t)512*128*2);
  ushort* dw2hi = (ushort*)alloc((size_t)256*128*2); ushort* dw2lo = (ushort*)alloc((size_t)256*128*2);
  ushort* decwhi= (ushort*)alloc((size_t)512*256*2); ushort* decwlo= (ushort*)alloc((size_t)512*256*2);
  float* bg1 = (float*)alloc(512*4); float* bg2 = (float*)alloc(512*4);
  float* bm1 = (float*)alloc(384*4);
  float* bg3 = (float*)alloc(512*4); float* bg4 = (float*)alloc(512*4);
  float* bm2 = (float*)alloc(256*4);
  (void)ws_size; (void)in_sizes; (void)n_in; (void)out_size;

  // region overlays
  ushort* maghi  = (ushort*)R1;                              // [BN][288]
  ushort* maglo  = (ushort*)(R1 + (size_t)BN * 288 * 2);
  float*  ENC    = (float*)R1;                               // [BN][256] (MAG dead)
  ushort* ENCNhi = (ushort*)(R1 + (size_t)BN * NE * 4);      // [BN][256]
  ushort* ENCNlo = (ushort*)(R1 + (size_t)BN * NE * 4 + (size_t)BN * NE * 2);
  ushort* Dhi    = ENCNhi;                                   // dec-in planes
  ushort* Dlo    = ENCNlo;
  ushort* Y1hi   = (ushort*)G;                               // [BN][512]
  ushort* Y1lo   = (ushort*)G + (size_t)BN * 512;

  const dim3 blk(256);
  auto ceilb = [](long n){ return (int)((n + 255) / 256); };

  // ---- prep ----
  fill_fwd<<<ceilb((long)512*512), blk, 0, stream>>>(fwdThi, fwdTlo);
  fill_inv<<<ceilb((long)512*544), blk, 0, stream>>>(invThi, invTlo);
  wconv_g<<<ceilb((long)512*288), blk, 0, stream>>>(s1_wih1, 257, w11hi, w11lo, 288);
  wconv_g<<<ceilb((long)512*128), blk, 0, stream>>>(s1_whh1, 128, wh1hi, wh1lo, 128);
  wconv_g<<<ceilb((long)512*128), blk, 0, stream>>>(s1_wih2, 128, w12hi, w12lo, 128);
  wconv_g<<<ceilb((long)512*128), blk, 0, stream>>>(s1_whh2, 128, wh2hi, wh2lo, 128);
  wconv<<<ceilb((long)384*128), blk, 0, stream>>>(s1_dw,   257, 128, dw1hi, dw1lo, 384, 128);
  wconv<<<ceilb((long)256*512), blk, 0, stream>>>(enc_w,   256, 512, encwhi, encwlo, 256, 512);
  wconv_g<<<ceilb((long)512*256), blk, 0, stream>>>(s2_wih1, 256, w21hi, w21lo, 256);
  wconv_g<<<ceilb((long)512*128), blk, 0, stream>>>(s2_whh1, 128, wh3hi, wh3lo, 128);
  wconv_g<<<ceilb((long)512*128), blk, 0, stream>>>(s2_wih2, 128, w22hi, w22lo, 128);
  wconv_g<<<ceilb((long)512*128), blk, 0, stream>>>(s2_whh2, 128, wh4hi, wh4lo, 128);
  wconv<<<ceilb((long)256*128), blk, 0, stream>>>(s2_dw,   256, 128, dw2hi, dw2lo, 256, 128);
  wconv<<<ceilb((long)512*256), blk, 0, stream>>>(dec_w,   512, 256, decwhi, decwlo, 512, 256);
  bias_g<<<2, blk, 0, stream>>>(s1_bih1, s1_bhh1, bg1);
  bias_g<<<2, blk, 0, stream>>>(s1_bih2, s1_bhh2, bg2);
  bias_pad<<<2, blk, 0, stream>>>(s1_db,   nullptr, 257, bm1, 384);
  bias_g<<<2, blk, 0, stream>>>(s2_bih1, s2_bhh1, bg3);
  bias_g<<<2, blk, 0, stream>>>(s2_bih2, s2_bhh2, bg4);
  bias_pad<<<1, blk, 0, stream>>>(s2_db,   nullptr, 256, bm2, 256);

  convert_x<<<ceilb((long)BN*544), blk, 0, stream>>>(x, XShi, XSlo);
  unpack_state<<<ceilb((long)BN*NH), blk, 0, stream>>>(st1, h1hi, h1lo, C1, h2hi, h2lo, C2);

  // ---- rfft (+fused magphase) + Nyquist ----
  mfma_gemm<M_RFFT><<<dim3(256,4), blk, 0, stream>>>(XShi, XSlo, 544, 512,
      fwdThi, fwdTlo, nullptr, nullptr, 0, 0, nullptr, nullptr,
      nullptr, RI, nullptr, nullptr, 514,
      nullptr, nullptr, nullptr, nullptr, maghi, maglo);
  nyq_kernel<<<BN/4, blk, 0, stream>>>(x, RI, maghi, maglo);

  // ---- sep block 1 (fused LSTM epilogues) ----
  mfma_gemm<M_LSTM><<<dim3(256,4), blk, 0, stream>>>(maghi, maglo, 288, 288,
      w11hi, w11lo, h1hi, h1lo, 128, 128, wh1hi, wh1lo,
      bg1, nullptr, nullptr, nullptr, 0,
      C1, nullptr, nullptr, out_st1, h1nhi, h1nlo);
  mfma_gemm<M_LSTM><<<dim3(256,4), blk, 0, stream>>>(h1nhi, h1nlo, 128, 128,
      w12hi, w12lo, h2hi, h2lo, 128, 128, wh2hi, wh2lo,
      bg2, nullptr, nullptr, nullptr, 0,
      C2, nullptr, nullptr, out_st1 + (size_t)BN*NH*2, h2nhi, h2nlo);
  // ---- mask1 + fused est_build -> XS planes ----
  mfma_gemm<M_EST><<<dim3(256,3), blk, 0, stream>>>(h2nhi, h2nlo, 128, 128,
      dw1hi, dw1lo, nullptr, nullptr, 0, 0, nullptr, nullptr,
      bm1, nullptr, nullptr, nullptr, 0,
      RI, maghi, maglo, nullptr, XShi, XSlo);

  // ---- irfft -> Y1 planes ----
  mfma_gemm<M_PLANES><<<dim3(256,4), blk, 0, stream>>>(XShi, XSlo, 544, 544,
      invThi, invTlo, nullptr, nullptr, 0, 0, nullptr, nullptr,
      nullptr, nullptr, Y1hi, Y1lo, 512,
      nullptr, nullptr, nullptr, nullptr, nullptr, nullptr);

  // ---- encoder + LN ----
  mfma_gemm<M_F32><<<dim3(256,2), blk, 0, stream>>>(Y1hi, Y1lo, 512, 512,
      encwhi, encwlo, nullptr, nullptr, 0, 0, nullptr, nullptr,
      nullptr, ENC, nullptr, nullptr, 256,
      nullptr, nullptr, nullptr, nullptr, nullptr, nullptr);
  ln_kernel<<<BN, 64, 0, stream>>>(ENC, ln_g, ln_b, ENCNhi, ENCNlo);

  // ---- sep block 2 ----
  unpack_state<<<ceilb((long)BN*NH), blk, 0, stream>>>(st2, h1hi, h1lo, C1, h2hi, h2lo, C2);
  mfma_gemm<M_LSTM><<<dim3(256,4), blk, 0, stream>>>(ENCNhi, ENCNlo, 256, 256,
      w21hi, w21lo, h1hi, h1lo, 128, 128, wh3hi, wh3lo,
      bg3, nullptr, nullptr, nullptr, 0,
      C1, nullptr, nullptr, out_st2, h1nhi, h1nlo);
  mfma_gemm<M_LSTM><<<dim3(256,4), blk, 0, stream>>>(h1nhi, h1nlo, 128, 128,
      w22hi, w22lo, h2hi, h2lo, 128, 128, wh4hi, wh4lo,
      bg4, nullptr, nullptr, nullptr, 0,
      C2, nullptr, nullptr, out_st2 + (size_t)BN*NH*2, h2nhi, h2nlo);
  // ---- mask2 + fused dec_in -> D planes ----
  mfma_gemm<M_DEC><<<dim3(256,2), blk, 0, stream>>>(h2nhi, h2nlo, 128, 128,
      dw2hi, dw2lo, nullptr, nullptr, 0, 0, nullptr, nullptr,
      bm2, nullptr, nullptr, nullptr, 0,
      ENC, nullptr, nullptr, nullptr, Dhi, Dlo);

  // ---- decoder ----
  mfma_gemm<M_F32><<<dim3(256,4), blk, 0, stream>>>(Dhi, Dlo, 256, 256,
      decwhi, decwlo, nullptr, nullptr, 0, 0, nullptr, nullptr,
      nullptr, out_dec, nullptr, nullptr, 512,
      nullptr, nullptr, nullptr, nullptr, nullptr, nullptr);
}

// Round 6
// 403.328 us; speedup vs baseline: 1.1752x; 1.0551x over previous
//
#include <hip/hip_runtime.h>
#include <hip/hip_bf16.h>
#include <math.h>

static constexpr int BN   = 16384;
static constexpr int NFFT = 512;
static constexpr int NBIN = 257;
static constexpr int NH   = 128;
static constexpr int NE   = 256;
static constexpr float EPSF  = 1.1920929e-07f;
static constexpr float LNEPS = 1e-07f;

using short8  = __attribute__((ext_vector_type(8))) short;
using float4v = __attribute__((ext_vector_type(4))) float;

__device__ __forceinline__ float sigm(float x){ return 1.0f/(1.0f+expf(-x)); }
__device__ __forceinline__ ushort f2b(float v){
  __hip_bfloat16 b = __float2bfloat16(v);
  return *reinterpret_cast<ushort*>(&b);
}
__device__ __forceinline__ float b2f(ushort u){
  __hip_bfloat16 b = *reinterpret_cast<__hip_bfloat16*>(&u);
  return __bfloat162float(b);
}

// ---- packed staging-ready layout ----
// matrix [rows][K] stored as chunks: chunk kt (32 k) x row -> 128B:
// 8 slots x 16B; slot p at row r holds LOGICAL slot p^(r&7);
// logical slots 0..3 = hi bf16 of k sub-chunks, 4..7 = lo bf16.
__device__ __forceinline__ size_t pkoff(int rows, int row, int k, int lo){
  const int ls = ((((k >> 3) & 3) | (lo << 2)) ^ (row & 7));
  return (size_t)(k >> 5) * ((size_t)rows << 6) + ((size_t)row << 6) + (ls << 3) + (k & 7);
}
__device__ __forceinline__ void split_pk(float v, ushort* base, int rows, int row, int k){
  ushort h = f2b(v);
  base[pkoff(rows, row, k, 0)] = h;
  base[pkoff(rows, row, k, 1)] = f2b(v - b2f(h));
}
__device__ __forceinline__ float read_pk(const ushort* base, int rows, int row, int k){
  return b2f(base[pkoff(rows, row, k, 0)]) + b2f(base[pkoff(rows, row, k, 1)]);
}

__device__ __forceinline__ void gload16(const ushort* g, ushort* l){
  __builtin_amdgcn_global_load_lds(
      (const __attribute__((address_space(1))) unsigned int*)g,
      (__attribute__((address_space(3))) unsigned int*)l,
      16, 0, 0);
}

// epilogue modes
enum { M_F32 = 0, M_PLANES = 1, M_LSTM = 2, M_EST = 3, M_DEC = 4, M_RFFT = 5 };

// ================= MFMA bf16x2 NT GEMM, BM=64 / BN=128, packed operands ====
// C[row][col] = sum_k A[row][k]*B[col][k] (+ optional phase2 A2/B2)
// Operands pre-packed (see pkoff): each global_load_lds reads 1KB contiguous.
// Tile 64x128, 4 waves of 32x64. Single-buffered 24KB LDS.
// MODE_LSTM expects gate-PERMUTED weights/bias: col' = 128*(u>>5)+32*g+(u&31).
template<int MODE>
__global__ __launch_bounds__(256)
void mfma_gemm(const ushort* __restrict__ Apk, int nkA,
               const ushort* __restrict__ Bpk, int MB,
               const ushort* __restrict__ A2pk, int nkA2,
               const ushort* __restrict__ B2pk, int MB2,
               const float* __restrict__ bias,
               float* __restrict__ C, int ldc,
               const float* __restrict__ aux0,   // LSTM: c_in | EST: RI | DEC: ENC
               const ushort* __restrict__ auxpk, // EST: mag packed
               float* __restrict__ out0,         // LSTM: out_state (h,c pairs)
               ushort* __restrict__ opk)         // packed output (h/XS/D/Y1/mag)
{
  constexpr int LDSW = (MODE == M_LSTM) ? 16384 : 12288;
  __shared__ ushort smem[LDSW];
  const int tid  = threadIdx.x;
  const int row0 = blockIdx.x * 64;
  const int col0 = blockIdx.y * 128;
  const int lane = tid & 63;
  const int wv   = tid >> 6;
  const int wr   = (wv >> 1) * 32;   // 0 / 32
  const int wc   = (wv & 1) * 64;    // 0 / 64
  const int fr   = lane & 15;
  const int quad = lane >> 4;

  float4v acc[2][4];
  #pragma unroll
  for (int i = 0; i < 2; ++i)
    #pragma unroll
    for (int j = 0; j < 4; ++j)
      acc[i][j] = float4v{0.f, 0.f, 0.f, 0.f};

  const int nt0 = nkA;
  const int nt1 = A2pk ? nkA2 : 0;
  const int nt  = nt0 + nt1;

  const size_t astr  = (size_t)BN << 6;
  const size_t bstr  = (size_t)MB << 6;
  const size_t bstr2 = (size_t)MB2 << 6;
  size_t abase[2], bbase[4];
  #pragma unroll
  for (int s = 0; s < 2; ++s)
    abase[s] = ((size_t)(row0 + (wv * 2 + s) * 8) << 6) + lane * 8;
  #pragma unroll
  for (int s = 0; s < 4; ++s)
    bbase[s] = ((size_t)(col0 + (wv * 4 + s) * 8) << 6) + lane * 8;

  #pragma unroll 1
  for (int t = 0; t < nt; ++t) {
    // ---- stage: each instruction = 1KB contiguous ----
    if (t < nt0) {
      #pragma unroll
      for (int s = 0; s < 2; ++s)
        gload16(Apk + (size_t)t * astr + abase[s], &smem[(wv * 2 + s) * 512]);
      #pragma unroll
      for (int s = 0; s < 4; ++s)
        gload16(Bpk + (size_t)t * bstr + bbase[s], &smem[4096 + (wv * 4 + s) * 512]);
    } else {
      const size_t kt = t - nt0;
      #pragma unroll
      for (int s = 0; s < 2; ++s)
        gload16(A2pk + kt * astr + abase[s], &smem[(wv * 2 + s) * 512]);
      #pragma unroll
      for (int s = 0; s < 4; ++s)
        gload16(B2pk + kt * bstr2 + bbase[s], &smem[4096 + (wv * 4 + s) * 512]);
    }
    asm volatile("s_waitcnt vmcnt(0)" ::: "memory");
    __syncthreads();

    // ---- fragments (swizzled reads) ----
    const char* Ab = (const char*)smem;
    const char* Bb = (const char*)(smem + 4096);
    short8 ah[2], al[2], bh[4], bl[4];
    #pragma unroll
    for (int i = 0; i < 2; ++i) {
      const int ra  = wr + i * 16 + fr;
      const int swa = (ra & 7) << 4;
      ah[i] = *(const short8*)(Ab + ra * 128 + ((quad << 4) ^ swa));
      al[i] = *(const short8*)(Ab + ra * 128 + ((64 | (quad << 4)) ^ swa));
    }
    #pragma unroll
    for (int j = 0; j < 4; ++j) {
      const int rb  = wc + j * 16 + fr;
      const int swb = (rb & 7) << 4;
      bh[j] = *(const short8*)(Bb + rb * 128 + ((quad << 4) ^ swb));
      bl[j] = *(const short8*)(Bb + rb * 128 + ((64 | (quad << 4)) ^ swb));
    }
    #pragma unroll
    for (int i = 0; i < 2; ++i)
      #pragma unroll
      for (int j = 0; j < 4; ++j) {
        acc[i][j] = __builtin_amdgcn_mfma_f32_16x16x32_bf16(ah[i], bh[j], acc[i][j], 0, 0, 0);
        acc[i][j] = __builtin_amdgcn_mfma_f32_16x16x32_bf16(ah[i], bl[j], acc[i][j], 0, 0, 0);
        acc[i][j] = __builtin_amdgcn_mfma_f32_16x16x32_bf16(al[i], bh[j], acc[i][j], 0, 0, 0);
      }
    __syncthreads();
  }

  // ---- epilogues; C/D layout: col=lane&15 group, row=quad*4+reg ----
  if constexpr (MODE == M_F32) {
    #pragma unroll
    for (int j = 0; j < 4; ++j) {
      const int colb = col0 + wc + j * 16 + fr;
      const float bv = bias ? bias[colb] : 0.f;
      #pragma unroll
      for (int i = 0; i < 2; ++i)
        #pragma unroll
        for (int r = 0; r < 4; ++r) {
          const int row = row0 + wr + i * 16 + quad * 4 + r;
          C[(size_t)row * ldc + colb] = acc[i][j][r] + bv;
        }
    }
  } else if constexpr (MODE == M_PLANES) {
    #pragma unroll
    for (int j = 0; j < 4; ++j) {
      const int colb = col0 + wc + j * 16 + fr;
      #pragma unroll
      for (int i = 0; i < 2; ++i)
        #pragma unroll
        for (int r = 0; r < 4; ++r) {
          const int row = row0 + wr + i * 16 + quad * 4 + r;
          split_pk(acc[i][j][r], opk, BN, row, colb);
        }
    }
  } else if constexpr (MODE == M_RFFT) {
    #pragma unroll
    for (int j = 0; j < 4; ++j) {
      const int colb = col0 + wc + j * 16 + fr;
      #pragma unroll
      for (int i = 0; i < 2; ++i)
        #pragma unroll
        for (int r = 0; r < 4; ++r) {
          const int row = row0 + wr + i * 16 + quad * 4 + r;
          const float v = acc[i][j][r];
          C[(size_t)row * ldc + colb] = v;
          const float w = __shfl_xor(v, 1, 64);
          if (!(lane & 1)) {
            const int bin = colb >> 1;
            const float mg = sqrtf(fmaxf(v * v + w * w, EPSF));
            split_pk(mg, opk, BN, row, bin);
          }
        }
    }
  } else if constexpr (MODE == M_EST) {
    #pragma unroll
    for (int j = 0; j < 4; ++j) {
      const int colg = col0 + wc + j * 16 + fr;   // bin index
      const float bv = bias[colg];
      #pragma unroll
      for (int i = 0; i < 2; ++i)
        #pragma unroll
        for (int r = 0; r < 4; ++r) {
          const int row = row0 + wr + i * 16 + quad * 4 + r;
          if (colg < NBIN) {
            const float m   = sigm(acc[i][j][r] + bv);
            const float mag = read_pk(auxpk, BN, row, colg);
            const float e   = m * mag;
            const float rr  = aux0[(size_t)row * 514 + 2 * colg];
            const float im  = aux0[(size_t)row * 514 + 2 * colg + 1];
            const float re = rr + EPSF, ie = im + EPSF;
            const float hyp = fmaxf(sqrtf(re * re + ie * ie), 1e-35f);
            split_pk(e * re / hyp, opk, BN, row, 2 * colg);
            split_pk(e * ie / hyp, opk, BN, row, 2 * colg + 1);
          } else if (colg < 272) {
            const int k0 = 2 * colg;
            opk[pkoff(BN, row, k0, 0)] = 0;     opk[pkoff(BN, row, k0, 1)] = 0;
            opk[pkoff(BN, row, k0 + 1, 0)] = 0; opk[pkoff(BN, row, k0 + 1, 1)] = 0;
          }
        }
    }
  } else if constexpr (MODE == M_DEC) {
    #pragma unroll
    for (int j = 0; j < 4; ++j) {
      const int colg = col0 + wc + j * 16 + fr;
      const float bv = bias[colg];
      #pragma unroll
      for (int i = 0; i < 2; ++i)
        #pragma unroll
        for (int r = 0; r < 4; ++r) {
          const int row = row0 + wr + i * 16 + quad * 4 + r;
          const float v = sigm(acc[i][j][r] + bv) * aux0[(size_t)row * NE + colg];
          split_pk(v, opk, BN, row, colg);
        }
    }
  } else {
    // M_LSTM: block's 128 cols = units ub..ub+31, gates 0..3 (permuted)
    float* Ep = (float*)smem;   // 64 rows x 128 gate-cols f32 = 32 KB
    const int ub = blockIdx.y << 5;
    #pragma unroll
    for (int j = 0; j < 4; ++j) {
      const int cl = wc + j * 16 + fr;
      const float bv = bias[col0 + cl];
      #pragma unroll
      for (int i = 0; i < 2; ++i)
        #pragma unroll
        for (int r = 0; r < 4; ++r)
          Ep[(wr + i * 16 + quad * 4 + r) * 128 + cl] = acc[i][j][r] + bv;
    }
    __syncthreads();
    #pragma unroll
    for (int k = 0; k < 8; ++k) {
      const int cell = tid + 256 * k;        // 0..2047
      const int ul = cell & 31;
      const int er = cell >> 5;              // 0..63
      const int row = row0 + er;
      const int unit = ub + ul;
      const float gi = Ep[er * 128 + ul];
      const float gf = Ep[er * 128 + 32 + ul];
      const float gc = Ep[er * 128 + 64 + ul];
      const float go = Ep[er * 128 + 96 + ul];
      const float cp = aux0[(size_t)row * NH + unit];
      const float cn = sigm(gf) * cp + sigm(gi) * tanhf(gc);
      const float hn = sigm(go) * tanhf(cn);
      split_pk(hn, opk, BN, row, unit);
      float2 hc; hc.x = hn; hc.y = cn;
      *(float2*)(out0 + 2 * ((size_t)row * NH + unit)) = hc;
    }
  }
}

// ================= weight / bias prep (packed) =================
__global__ void wconv_pk(const float* __restrict__ src, int M0, int K0,
                         ushort* __restrict__ dst, int Mp, int Kp){
  int idx = blockIdx.x * blockDim.x + threadIdx.x;
  if (idx >= Mp * Kp) return;
  int r = idx / Kp, k = idx - r * Kp;
  float v = (r < M0 && k < K0) ? src[(size_t)r * K0 + k] : 0.f;
  split_pk(v, dst, Mp, r, k);
}

// gate-permuted: dst row r' <- src row g*128+u; r' = 128*(u>>5)+32*g+(u&31)
__global__ void wconv_g_pk(const float* __restrict__ src, int K0,
                           ushort* __restrict__ dst, int Kp){
  int idx = blockIdx.x * blockDim.x + threadIdx.x;
  if (idx >= 512 * Kp) return;
  int rp = idx / Kp, k = idx - rp * Kp;
  int y = rp >> 7, g = (rp >> 5) & 3, u = (y << 5) | (rp & 31);
  float v = (k < K0) ? src[(size_t)(g * 128 + u) * K0 + k] : 0.f;
  split_pk(v, dst, 512, rp, k);
}

__global__ void bias_pad(const float* __restrict__ s1, const float* __restrict__ s2,
                         int L, float* __restrict__ dst, int Lp){
  int idx = blockIdx.x * blockDim.x + threadIdx.x;
  if (idx >= Lp) return;
  float v = 0.f;
  if (idx < L) { v = s1[idx]; if (s2) v += s2[idx]; }
  dst[idx] = v;
}

__global__ void bias_g(const float* __restrict__ s1, const float* __restrict__ s2,
                       float* __restrict__ dst){
  int rp = blockIdx.x * blockDim.x + threadIdx.x;
  if (rp >= 512) return;
  int y = rp >> 7, g = (rp >> 5) & 3, u = (y << 5) | (rp & 31);
  int sr = g * 128 + u;
  dst[rp] = s1[sr] + s2[sr];
}

// fwdT [512 cols][512 n]: col c=2k -> cos(2pi k n/512), c=2k+1 -> -sin
__global__ void fill_fwd_pk(ushort* __restrict__ dst){
  int idx = blockIdx.x * blockDim.x + threadIdx.x;
  if (idx >= 512 * 512) return;
  int c = idx >> 9, n = idx & 511;
  int k = c >> 1, m = (k * n) & 511;
  float th = (float)m * (6.283185307179586f / 512.0f);
  float s, co; sincosf(th, &s, &co);
  float v = (c & 1) ? -s : co;
  split_pk(v, dst, 512, c, n);
}

// invT [512 n][544 c]: c=2k -> w_k cos, c=2k+1 -> -w_k sin; c=512 Nyquist
__global__ void fill_inv_pk(ushort* __restrict__ dst){
  int idx = blockIdx.x * blockDim.x + threadIdx.x;
  if (idx >= 512 * 544) return;
  int n = idx / 544, c = idx - n * 544;
  float v = 0.f;
  if (c < 512) {
    int k = c >> 1, m = (k * n) & 511;
    float th = (float)m * (6.283185307179586f / 512.0f);
    float s, co; sincosf(th, &s, &co);
    float w = (k == 0) ? (1.0f / 512.0f) : (2.0f / 512.0f);
    v = (c & 1) ? -w * s : w * co;
  } else if (c == 512) {
    v = ((n & 1) ? -1.0f : 1.0f) / 512.0f;
  }
  split_pk(v, dst, 512, n, c);
}

// ================= elementwise =================
__global__ void convert_x_pk(const float* __restrict__ x, ushort* __restrict__ dst){
  int idx = blockIdx.x * blockDim.x + threadIdx.x;
  if (idx >= BN * 544) return;
  int r = idx / 544, c = idx - r * 544;
  float v = (c < 512) ? x[(size_t)r * 512 + c] : 0.f;
  split_pk(v, dst, BN, r, c);
}

// Nyquist: RI[n][512]=sum x*(-1)^i, RI[n][513]=0, mag bins 256..287
__global__ void nyq_kernel(const float* __restrict__ x, float* __restrict__ RI,
                           ushort* __restrict__ magpk){
  int row  = blockIdx.x * 4 + (threadIdx.x >> 6);
  int lane = threadIdx.x & 63;
  const float* xr = x + (size_t)row * 512;
  float s = 0.f;
  #pragma unroll
  for (int i = 0; i < 8; ++i) {
    int n = lane + 64 * i;
    float v = xr[n];
    s += (n & 1) ? -v : v;
  }
  #pragma unroll
  for (int off = 32; off >= 1; off >>= 1) s += __shfl_xor(s, off, 64);
  if (lane == 0) {
    RI[(size_t)row * 514 + 512] = s;
    RI[(size_t)row * 514 + 513] = 0.f;
  }
  if (lane < 32) {
    float mg = (lane == 0) ? sqrtf(fmaxf(s * s, EPSF)) : 0.f;
    split_pk(mg, magpk, BN, row, 256 + lane);
  }
}

// in_state (2,BN,NH,2) f32 -> packed h + C f32 (both layers)
__global__ void unpack_state(const float* __restrict__ st,
                             ushort* __restrict__ h1pk, float* __restrict__ c1,
                             ushort* __restrict__ h2pk, float* __restrict__ c2){
  int idx = blockIdx.x * blockDim.x + threadIdx.x;
  if (idx >= BN * NH) return;
  int row = idx >> 7, u = idx & 127;
  split_pk(st[(size_t)idx * 2], h1pk, BN, row, u);
  c1[idx] = st[(size_t)idx * 2 + 1];
  size_t off = (size_t)BN * NH * 2;
  split_pk(st[off + (size_t)idx * 2], h2pk, BN, row, u);
  c2[idx] = st[off + (size_t)idx * 2 + 1];
}

// LayerNorm over 256 -> packed ENCN
__global__ void ln_kernel(const float* __restrict__ ENC,
                          const float* __restrict__ gamma,
                          const float* __restrict__ beta,
                          ushort* __restrict__ opk){
  int row = blockIdx.x;
  int t = threadIdx.x;   // 64; thread handles cols 4t..4t+3
  const float* e = ENC + (size_t)row * NE;
  float v[4]; float s = 0.f;
  #pragma unroll
  for (int i = 0; i < 4; ++i) { v[i] = e[4 * t + i]; s += v[i]; }
  #pragma unroll
  for (int off = 32; off >= 1; off >>= 1) s += __shfl_xor(s, off, 64);
  float mean = s * (1.0f / NE);
  float d[4]; float ss = 0.f;
  #pragma unroll
  for (int i = 0; i < 4; ++i) { d[i] = v[i] - mean; ss += d[i] * d[i]; }
  #pragma unroll
  for (int off = 32; off >= 1; off >>= 1) ss += __shfl_xor(ss, off, 64);
  float inv = 1.0f / sqrtf(ss * (1.0f / NE) + LNEPS);
  #pragma unroll
  for (int i = 0; i < 4; ++i) {
    int col = 4 * t + i;
    float o = d[i] * inv * gamma[col] + beta[col];
    split_pk(o, opk, BN, row, col);
  }
}

// ================= launch =================
extern "C" void kernel_launch(void* const* d_in, const int* in_sizes, int n_in,
                              void* d_out, int out_size, void* d_ws, size_t ws_size,
                              hipStream_t stream)
{
  const float* x       = (const float*)d_in[0];
  const float* st1     = (const float*)d_in[1];
  const float* st2     = (const float*)d_in[2];
  const float* s1_wih1 = (const float*)d_in[3];
  const float* s1_whh1 = (const float*)d_in[4];
  const float* s1_bih1 = (const float*)d_in[5];
  const float* s1_bhh1 = (const float*)d_in[6];
  const float* s1_wih2 = (const float*)d_in[7];
  const float* s1_whh2 = (const float*)d_in[8];
  const float* s1_bih2 = (const float*)d_in[9];
  const float* s1_bhh2 = (const float*)d_in[10];
  const float* s1_dw   = (const float*)d_in[11];
  const float* s1_db   = (const float*)d_in[12];
  const float* enc_w   = (const float*)d_in[13];
  const float* ln_g    = (const float*)d_in[14];
  const float* ln_b    = (const float*)d_in[15];
  const float* s2_wih1 = (const float*)d_in[16];
  const float* s2_whh1 = (const float*)d_in[17];
  const float* s2_bih1 = (const float*)d_in[18];
  const float* s2_bhh1 = (const float*)d_in[19];
  const float* s2_wih2 = (const float*)d_in[20];
  const float* s2_whh2 = (const float*)d_in[21];
  const float* s2_bih2 = (const float*)d_in[22];
  const float* s2_bhh2 = (const float*)d_in[23];
  const float* s2_dw   = (const float*)d_in[24];
  const float* s2_db   = (const float*)d_in[25];
  const float* dec_w   = (const float*)d_in[26];

  float* out_dec = (float*)d_out;
  float* out_st1 = out_dec + (size_t)BN * NFFT;
  float* out_st2 = out_st1 + (size_t)2 * BN * NH * 2;

  // ---- workspace (all packed buffers separate; ~230 MB total) ----
  char* base = (char*)d_ws;
  size_t off = 0;
  auto alloc = [&](size_t bytes) -> void* {
    off = (off + 255) & ~(size_t)255;
    void* p = base + off;
    off += bytes;
    return p;
  };
  auto pkbytes = [](int rows, int nk) -> size_t {
    return (size_t)nk * rows * 64 * 2;
  };
  ushort* fwdTpk = (ushort*)alloc(pkbytes(512, 16));
  ushort* invTpk = (ushort*)alloc(pkbytes(512, 17));
  ushort* XSpk   = (ushort*)alloc(pkbytes(BN, 17));
  float*  RI     = (float*) alloc((size_t)BN * 514 * 4);
  ushort* magpk  = (ushort*)alloc(pkbytes(BN, 9));
  ushort* Y1pk   = (ushort*)alloc(pkbytes(BN, 16));
  float*  ENC    = (float*) alloc((size_t)BN * NE * 4);
  ushort* ENCNpk = (ushort*)alloc(pkbytes(BN, 8));
  ushort* Dpk    = (ushort*)alloc(pkbytes(BN, 8));
  ushort* h1pk   = (ushort*)alloc(pkbytes(BN, 4));
  ushort* h2pk   = (ushort*)alloc(pkbytes(BN, 4));
  ushort* h1npk  = (ushort*)alloc(pkbytes(BN, 4));
  ushort* h2npk  = (ushort*)alloc(pkbytes(BN, 4));
  float*  C1     = (float*) alloc((size_t)BN * NH * 4);
  float*  C2     = (float*) alloc((size_t)BN * NH * 4);
  ushort* w11pk  = (ushort*)alloc(pkbytes(512, 9));
  ushort* wh1pk  = (ushort*)alloc(pkbytes(512, 4));
  ushort* w12pk  = (ushort*)alloc(pkbytes(512, 4));
  ushort* wh2pk  = (ushort*)alloc(pkbytes(512, 4));
  ushort* dw1pk  = (ushort*)alloc(pkbytes(384, 4));
  ushort* encwpk = (ushort*)alloc(pkbytes(256, 16));
  ushort* w21pk  = (ushort*)alloc(pkbytes(512, 8));
  ushort* wh3pk  = (ushort*)alloc(pkbytes(512, 4));
  ushort* w22pk  = (ushort*)alloc(pkbytes(512, 4));
  ushort* wh4pk  = (ushort*)alloc(pkbytes(512, 4));
  ushort* dw2pk  = (ushort*)alloc(pkbytes(256, 4));
  ushort* decwpk = (ushort*)alloc(pkbytes(512, 8));
  float* bg1 = (float*)alloc(512*4); float* bg2 = (float*)alloc(512*4);
  float* bm1 = (float*)alloc(384*4);
  float* bg3 = (float*)alloc(512*4); float* bg4 = (float*)alloc(512*4);
  float* bm2 = (float*)alloc(256*4);
  (void)ws_size; (void)in_sizes; (void)n_in; (void)out_size;

  const dim3 blk(256);
  auto ceilb = [](long n){ return (int)((n + 255) / 256); };

  // ---- prep ----
  fill_fwd_pk<<<ceilb((long)512*512), blk, 0, stream>>>(fwdTpk);
  fill_inv_pk<<<ceilb((long)512*544), blk, 0, stream>>>(invTpk);
  wconv_g_pk<<<ceilb((long)512*288), blk, 0, stream>>>(s1_wih1, 257, w11pk, 288);
  wconv_g_pk<<<ceilb((long)512*128), blk, 0, stream>>>(s1_whh1, 128, wh1pk, 128);
  wconv_g_pk<<<ceilb((long)512*128), blk, 0, stream>>>(s1_wih2, 128, w12pk, 128);
  wconv_g_pk<<<ceilb((long)512*128), blk, 0, stream>>>(s1_whh2, 128, wh2pk, 128);
  wconv_pk<<<ceilb((long)384*128), blk, 0, stream>>>(s1_dw,   257, 128, dw1pk, 384, 128);
  wconv_pk<<<ceilb((long)256*512), blk, 0, stream>>>(enc_w,   256, 512, encwpk, 256, 512);
  wconv_g_pk<<<ceilb((long)512*256), blk, 0, stream>>>(s2_wih1, 256, w21pk, 256);
  wconv_g_pk<<<ceilb((long)512*128), blk, 0, stream>>>(s2_whh1, 128, wh3pk, 128);
  wconv_g_pk<<<ceilb((long)512*128), blk, 0, stream>>>(s2_wih2, 128, w22pk, 128);
  wconv_g_pk<<<ceilb((long)512*128), blk, 0, stream>>>(s2_whh2, 128, wh4pk, 128);
  wconv_pk<<<ceilb((long)256*128), blk, 0, stream>>>(s2_dw,   256, 128, dw2pk, 256, 128);
  wconv_pk<<<ceilb((long)512*256), blk, 0, stream>>>(dec_w,   512, 256, decwpk, 512, 256);
  bias_g<<<2, blk, 0, stream>>>(s1_bih1, s1_bhh1, bg1);
  bias_g<<<2, blk, 0, stream>>>(s1_bih2, s1_bhh2, bg2);
  bias_pad<<<2, blk, 0, stream>>>(s1_db,   nullptr, 257, bm1, 384);
  bias_g<<<2, blk, 0, stream>>>(s2_bih1, s2_bhh1, bg3);
  bias_g<<<2, blk, 0, stream>>>(s2_bih2, s2_bhh2, bg4);
  bias_pad<<<1, blk, 0, stream>>>(s2_db,   nullptr, 256, bm2, 256);

  convert_x_pk<<<ceilb((long)BN*544), blk, 0, stream>>>(x, XSpk);
  unpack_state<<<ceilb((long)BN*NH), blk, 0, stream>>>(st1, h1pk, C1, h2pk, C2);

  // ---- rfft (+fused magphase) + Nyquist ----
  mfma_gemm<M_RFFT><<<dim3(256,4), blk, 0, stream>>>(XSpk, 16, fwdTpk, 512,
      nullptr, 0, nullptr, 0,
      nullptr, RI, 514, nullptr, nullptr, nullptr, magpk);
  nyq_kernel<<<BN/4, blk, 0, stream>>>(x, RI, magpk);

  // ---- sep block 1 (fused LSTM epilogues) ----
  mfma_gemm<M_LSTM><<<dim3(256,4), blk, 0, stream>>>(magpk, 9, w11pk, 512,
      h1pk, 4, wh1pk, 512,
      bg1, nullptr, 0, C1, nullptr, out_st1, h1npk);
  mfma_gemm<M_LSTM><<<dim3(256,4), blk, 0, stream>>>(h1npk, 4, w12pk, 512,
      h2pk, 4, wh2pk, 512,
      bg2, nullptr, 0, C2, nullptr, out_st1 + (size_t)BN*NH*2, h2npk);
  // ---- mask1 + fused est_build -> XS packed ----
  mfma_gemm<M_EST><<<dim3(256,3), blk, 0, stream>>>(h2npk, 4, dw1pk, 384,
      nullptr, 0, nullptr, 0,
      bm1, nullptr, 0, RI, magpk, nullptr, XSpk);

  // ---- irfft -> Y1 packed ----
  mfma_gemm<M_PLANES><<<dim3(256,4), blk, 0, stream>>>(XSpk, 17, invTpk, 512,
      nullptr, 0, nullptr, 0,
      nullptr, nullptr, 0, nullptr, nullptr, nullptr, Y1pk);

  // ---- encoder + LN ----
  mfma_gemm<M_F32><<<dim3(256,2), blk, 0, stream>>>(Y1pk, 16, encwpk, 256,
      nullptr, 0, nullptr, 0,
      nullptr, ENC, 256, nullptr, nullptr, nullptr, nullptr);
  ln_kernel<<<BN, 64, 0, stream>>>(ENC, ln_g, ln_b, ENCNpk);

  // ---- sep block 2 ----
  unpack_state<<<ceilb((long)BN*NH), blk, 0, stream>>>(st2, h1pk, C1, h2pk, C2);
  mfma_gemm<M_LSTM><<<dim3(256,4), blk, 0, stream>>>(ENCNpk, 8, w21pk, 512,
      h1pk, 4, wh3pk, 512,
      bg3, nullptr, 0, C1, nullptr, out_st2, h1npk);
  mfma_gemm<M_LSTM><<<dim3(256,4), blk, 0, stream>>>(h1npk, 4, w22pk, 512,
      h2pk, 4, wh4pk, 512,
      bg4, nullptr, 0, C2, nullptr, out_st2 + (size_t)BN*NH*2, h2npk);
  // ---- mask2 + fused dec_in -> D packed ----
  mfma_gemm<M_DEC><<<dim3(256,2), blk, 0, stream>>>(h2npk, 4, dw2pk, 256,
      nullptr, 0, nullptr, 0,
      bm2, nullptr, 0, ENC, nullptr, nullptr, Dpk);

  // ---- decoder ----
  mfma_gemm<M_F32><<<dim3(256,4), blk, 0, stream>>>(Dpk, 8, decwpk, 512,
      nullptr, 0, nullptr, 0,
      nullptr, out_dec, 512, nullptr, nullptr, nullptr, nullptr);
}

// Round 7
// 367.613 us; speedup vs baseline: 1.2894x; 1.0972x over previous
//
#include <hip/hip_runtime.h>
#include <hip/hip_bf16.h>
#include <math.h>

static constexpr int BN   = 16384;
static constexpr int NFFT = 512;
static constexpr int NBIN = 257;
static constexpr int NH   = 128;
static constexpr int NE   = 256;
static constexpr float EPSF  = 1.1920929e-07f;
static constexpr float LNEPS = 1e-07f;

using short8  = __attribute__((ext_vector_type(8))) short;
using float4v = __attribute__((ext_vector_type(4))) float;

__device__ __forceinline__ float sigm(float x){ return 1.0f/(1.0f+expf(-x)); }
__device__ __forceinline__ ushort f2b(float v){
  __hip_bfloat16 b = __float2bfloat16(v);
  return *reinterpret_cast<ushort*>(&b);
}
__device__ __forceinline__ float b2f(ushort u){
  __hip_bfloat16 b = *reinterpret_cast<__hip_bfloat16*>(&u);
  return __bfloat162float(b);
}

// ---- packed staging-ready layout ----
// matrix [rows][K] stored as chunks: chunk kt (32 k) x row -> 128B:
// 8 slots x 16B; slot p at row r holds LOGICAL slot p^(r&7);
// logical slots 0..3 = hi bf16 of k sub-chunks, 4..7 = lo bf16.
__device__ __forceinline__ size_t pkoff(int rows, int row, int k, int lo){
  const int ls = ((((k >> 3) & 3) | (lo << 2)) ^ (row & 7));
  return (size_t)(k >> 5) * ((size_t)rows << 6) + ((size_t)row << 6) + (ls << 3) + (k & 7);
}
__device__ __forceinline__ void split_pk(float v, ushort* base, int rows, int row, int k){
  ushort h = f2b(v);
  base[pkoff(rows, row, k, 0)] = h;
  base[pkoff(rows, row, k, 1)] = f2b(v - b2f(h));
}
__device__ __forceinline__ float read_pk(const ushort* base, int rows, int row, int k){
  return b2f(base[pkoff(rows, row, k, 0)]) + b2f(base[pkoff(rows, row, k, 1)]);
}

__device__ __forceinline__ void gload16(const ushort* g, ushort* l){
  __builtin_amdgcn_global_load_lds(
      (const __attribute__((address_space(1))) unsigned int*)g,
      (__attribute__((address_space(3))) unsigned int*)l,
      16, 0, 0);
}

// epilogue modes
enum { M_F32 = 0, M_PLANES = 1, M_LSTM = 2, M_EST = 3, M_DEC = 4, M_RFFT = 5 };

// ================= MFMA bf16x2 NT GEMM, BM=64 / BN=128, packed operands ====
// C[row][col] = sum_k A[row][k]*B[col][k] (+ optional phase2 A2/B2)
// Operands pre-packed (see pkoff): each global_load_lds reads 1KB contiguous.
// Tile 64x128, 4 waves of 32x64. Single-buffered 24KB LDS. MA = rows of A.
// M_PLANES: packed output with `ldc` = rows of output matrix.
// MODE_LSTM expects gate-PERMUTED weights/bias: col' = 128*(u>>5)+32*g+(u&31).
template<int MODE>
__global__ __launch_bounds__(256)
void mfma_gemm(const ushort* __restrict__ Apk, int MA, int nkA,
               const ushort* __restrict__ Bpk, int MB,
               const ushort* __restrict__ A2pk, int nkA2,
               const ushort* __restrict__ B2pk, int MB2,
               const float* __restrict__ bias,
               float* __restrict__ C, int ldc,
               const float* __restrict__ aux0,   // LSTM: c_in | EST: RI | DEC: ENC
               const ushort* __restrict__ auxpk, // EST: mag packed
               float* __restrict__ out0,         // LSTM: out_state (h,c pairs)
               ushort* __restrict__ opk)         // packed output
{
  constexpr int LDSW = (MODE == M_LSTM) ? 16384 : 12288;
  __shared__ ushort smem[LDSW];
  const int tid  = threadIdx.x;
  const int row0 = blockIdx.x * 64;
  const int col0 = blockIdx.y * 128;
  const int lane = tid & 63;
  const int wv   = tid >> 6;
  const int wr   = (wv >> 1) * 32;   // 0 / 32
  const int wc   = (wv & 1) * 64;    // 0 / 64
  const int fr   = lane & 15;
  const int quad = lane >> 4;

  float4v acc[2][4];
  #pragma unroll
  for (int i = 0; i < 2; ++i)
    #pragma unroll
    for (int j = 0; j < 4; ++j)
      acc[i][j] = float4v{0.f, 0.f, 0.f, 0.f};

  const int nt0 = nkA;
  const int nt1 = A2pk ? nkA2 : 0;
  const int nt  = nt0 + nt1;

  const size_t astr  = (size_t)MA << 6;
  const size_t bstr  = (size_t)MB << 6;
  const size_t bstr2 = (size_t)MB2 << 6;
  size_t abase[2], bbase[4];
  #pragma unroll
  for (int s = 0; s < 2; ++s)
    abase[s] = ((size_t)(row0 + (wv * 2 + s) * 8) << 6) + lane * 8;
  #pragma unroll
  for (int s = 0; s < 4; ++s)
    bbase[s] = ((size_t)(col0 + (wv * 4 + s) * 8) << 6) + lane * 8;

  #pragma unroll 1
  for (int t = 0; t < nt; ++t) {
    // ---- stage: each instruction = 1KB contiguous ----
    if (t < nt0) {
      #pragma unroll
      for (int s = 0; s < 2; ++s)
        gload16(Apk + (size_t)t * astr + abase[s], &smem[(wv * 2 + s) * 512]);
      #pragma unroll
      for (int s = 0; s < 4; ++s)
        gload16(Bpk + (size_t)t * bstr + bbase[s], &smem[4096 + (wv * 4 + s) * 512]);
    } else {
      const size_t kt = t - nt0;
      #pragma unroll
      for (int s = 0; s < 2; ++s)
        gload16(A2pk + kt * astr + abase[s], &smem[(wv * 2 + s) * 512]);
      #pragma unroll
      for (int s = 0; s < 4; ++s)
        gload16(B2pk + kt * bstr2 + bbase[s], &smem[4096 + (wv * 4 + s) * 512]);
    }
    asm volatile("s_waitcnt vmcnt(0)" ::: "memory");
    __syncthreads();

    // ---- fragments (swizzled reads) ----
    const char* Ab = (const char*)smem;
    const char* Bb = (const char*)(smem + 4096);
    short8 ah[2], al[2], bh[4], bl[4];
    #pragma unroll
    for (int i = 0; i < 2; ++i) {
      const int ra  = wr + i * 16 + fr;
      const int swa = (ra & 7) << 4;
      ah[i] = *(const short8*)(Ab + ra * 128 + ((quad << 4) ^ swa));
      al[i] = *(const short8*)(Ab + ra * 128 + ((64 | (quad << 4)) ^ swa));
    }
    #pragma unroll
    for (int j = 0; j < 4; ++j) {
      const int rb  = wc + j * 16 + fr;
      const int swb = (rb & 7) << 4;
      bh[j] = *(const short8*)(Bb + rb * 128 + ((quad << 4) ^ swb));
      bl[j] = *(const short8*)(Bb + rb * 128 + ((64 | (quad << 4)) ^ swb));
    }
    #pragma unroll
    for (int i = 0; i < 2; ++i)
      #pragma unroll
      for (int j = 0; j < 4; ++j) {
        acc[i][j] = __builtin_amdgcn_mfma_f32_16x16x32_bf16(ah[i], bh[j], acc[i][j], 0, 0, 0);
        acc[i][j] = __builtin_amdgcn_mfma_f32_16x16x32_bf16(ah[i], bl[j], acc[i][j], 0, 0, 0);
        acc[i][j] = __builtin_amdgcn_mfma_f32_16x16x32_bf16(al[i], bh[j], acc[i][j], 0, 0, 0);
      }
    __syncthreads();
  }

  // ---- epilogues; C/D layout: col=lane&15 group, row=quad*4+reg ----
  if constexpr (MODE == M_F32) {
    #pragma unroll
    for (int j = 0; j < 4; ++j) {
      const int colb = col0 + wc + j * 16 + fr;
      const float bv = bias ? bias[colb] : 0.f;
      #pragma unroll
      for (int i = 0; i < 2; ++i)
        #pragma unroll
        for (int r = 0; r < 4; ++r) {
          const int row = row0 + wr + i * 16 + quad * 4 + r;
          C[(size_t)row * ldc + colb] = acc[i][j][r] + bv;
        }
    }
  } else if constexpr (MODE == M_PLANES) {
    #pragma unroll
    for (int j = 0; j < 4; ++j) {
      const int colb = col0 + wc + j * 16 + fr;
      #pragma unroll
      for (int i = 0; i < 2; ++i)
        #pragma unroll
        for (int r = 0; r < 4; ++r) {
          const int row = row0 + wr + i * 16 + quad * 4 + r;
          split_pk(acc[i][j][r], opk, ldc, row, colb);   // ldc = rows of output
        }
    }
  } else if constexpr (MODE == M_RFFT) {
    #pragma unroll
    for (int j = 0; j < 4; ++j) {
      const int colb = col0 + wc + j * 16 + fr;
      #pragma unroll
      for (int i = 0; i < 2; ++i)
        #pragma unroll
        for (int r = 0; r < 4; ++r) {
          const int row = row0 + wr + i * 16 + quad * 4 + r;
          const float v = acc[i][j][r];
          C[(size_t)row * ldc + colb] = v;
          const float w = __shfl_xor(v, 1, 64);
          if (!(lane & 1)) {
            const int bin = colb >> 1;
            const float mg = sqrtf(fmaxf(v * v + w * w, EPSF));
            split_pk(mg, opk, BN, row, bin);
          }
        }
    }
  } else if constexpr (MODE == M_EST) {
    #pragma unroll
    for (int j = 0; j < 4; ++j) {
      const int colg = col0 + wc + j * 16 + fr;   // bin index
      const float bv = bias[colg];
      #pragma unroll
      for (int i = 0; i < 2; ++i)
        #pragma unroll
        for (int r = 0; r < 4; ++r) {
          const int row = row0 + wr + i * 16 + quad * 4 + r;
          if (colg < NBIN) {
            const float m   = sigm(acc[i][j][r] + bv);
            const float mag = read_pk(auxpk, BN, row, colg);
            const float e   = m * mag;
            const float rr  = aux0[(size_t)row * 514 + 2 * colg];
            const float im  = aux0[(size_t)row * 514 + 2 * colg + 1];
            const float re = rr + EPSF, ie = im + EPSF;
            const float hyp = fmaxf(sqrtf(re * re + ie * ie), 1e-35f);
            split_pk(e * re / hyp, opk, BN, row, 2 * colg);
            split_pk(e * ie / hyp, opk, BN, row, 2 * colg + 1);
          } else if (colg < 272) {
            const int k0 = 2 * colg;
            opk[pkoff(BN, row, k0, 0)] = 0;     opk[pkoff(BN, row, k0, 1)] = 0;
            opk[pkoff(BN, row, k0 + 1, 0)] = 0; opk[pkoff(BN, row, k0 + 1, 1)] = 0;
          }
        }
    }
  } else if constexpr (MODE == M_DEC) {
    #pragma unroll
    for (int j = 0; j < 4; ++j) {
      const int colg = col0 + wc + j * 16 + fr;
      const float bv = bias[colg];
      #pragma unroll
      for (int i = 0; i < 2; ++i)
        #pragma unroll
        for (int r = 0; r < 4; ++r) {
          const int row = row0 + wr + i * 16 + quad * 4 + r;
          const float v = sigm(acc[i][j][r] + bv) * aux0[(size_t)row * NE + colg];
          split_pk(v, opk, BN, row, colg);
        }
    }
  } else {
    // M_LSTM: block's 128 cols = units ub..ub+31, gates 0..3 (permuted)
    float* Ep = (float*)smem;   // 64 rows x 128 gate-cols f32 = 32 KB
    const int ub = blockIdx.y << 5;
    #pragma unroll
    for (int j = 0; j < 4; ++j) {
      const int cl = wc + j * 16 + fr;
      const float bv = bias[col0 + cl];
      #pragma unroll
      for (int i = 0; i < 2; ++i)
        #pragma unroll
        for (int r = 0; r < 4; ++r)
          Ep[(wr + i * 16 + quad * 4 + r) * 128 + cl] = acc[i][j][r] + bv;
    }
    __syncthreads();
    #pragma unroll
    for (int k = 0; k < 8; ++k) {
      const int cell = tid + 256 * k;        // 0..2047
      const int ul = cell & 31;
      const int er = cell >> 5;              // 0..63
      const int row = row0 + er;
      const int unit = ub + ul;
      const float gi = Ep[er * 128 + ul];
      const float gf = Ep[er * 128 + 32 + ul];
      const float gc = Ep[er * 128 + 64 + ul];
      const float go = Ep[er * 128 + 96 + ul];
      const float cp = aux0[(size_t)row * NH + unit];
      const float cn = sigm(gf) * cp + sigm(gi) * tanhf(gc);
      const float hn = sigm(go) * tanhf(cn);
      split_pk(hn, opk, BN, row, unit);
      float2 hc; hc.x = hn; hc.y = cn;
      *(float2*)(out0 + 2 * ((size_t)row * NH + unit)) = hc;
    }
  }
}

// ================= weight / bias prep (packed) =================
__global__ void wconv_pk(const float* __restrict__ src, int M0, int K0,
                         ushort* __restrict__ dst, int Mp, int Kp){
  int idx = blockIdx.x * blockDim.x + threadIdx.x;
  if (idx >= Mp * Kp) return;
  int r = idx / Kp, k = idx - r * Kp;
  float v = (r < M0 && k < K0) ? src[(size_t)r * K0 + k] : 0.f;
  split_pk(v, dst, Mp, r, k);
}

// gate-permuted: dst row r' <- src row g*128+u; r' = 128*(u>>5)+32*g+(u&31)
__global__ void wconv_g_pk(const float* __restrict__ src, int K0,
                           ushort* __restrict__ dst, int Kp){
  int idx = blockIdx.x * blockDim.x + threadIdx.x;
  if (idx >= 512 * Kp) return;
  int rp = idx / Kp, k = idx - rp * Kp;
  int y = rp >> 7, g = (rp >> 5) & 3, u = (y << 5) | (rp & 31);
  float v = (k < K0) ? src[(size_t)(g * 128 + u) * K0 + k] : 0.f;
  split_pk(v, dst, 512, rp, k);
}

__global__ void bias_pad(const float* __restrict__ s1, const float* __restrict__ s2,
                         int L, float* __restrict__ dst, int Lp){
  int idx = blockIdx.x * blockDim.x + threadIdx.x;
  if (idx >= Lp) return;
  float v = 0.f;
  if (idx < L) { v = s1[idx]; if (s2) v += s2[idx]; }
  dst[idx] = v;
}

__global__ void bias_g(const float* __restrict__ s1, const float* __restrict__ s2,
                       float* __restrict__ dst){
  int rp = blockIdx.x * blockDim.x + threadIdx.x;
  if (rp >= 512) return;
  int y = rp >> 7, g = (rp >> 5) & 3, u = (y << 5) | (rp & 31);
  int sr = g * 128 + u;
  dst[rp] = s1[sr] + s2[sr];
}

// fwdT [512 cols][512 n]: col c=2k -> cos(2pi k n/512), c=2k+1 -> -sin
__global__ void fill_fwd_pk(ushort* __restrict__ dst){
  int idx = blockIdx.x * blockDim.x + threadIdx.x;
  if (idx >= 512 * 512) return;
  int c = idx >> 9, n = idx & 511;
  int k = c >> 1, m = (k * n) & 511;
  float th = (float)m * (6.283185307179586f / 512.0f);
  float s, co; sincosf(th, &s, &co);
  float v = (c & 1) ? -s : co;
  split_pk(v, dst, 512, c, n);
}

// invT TRANSPOSED packed [640 rows=c][512 k=n]:
// row c=2k -> w_k cos(2pi k n/512), c=2k+1 -> -w_k sin; c=512 Nyquist; c>512: 0
__global__ void fill_invTt_pk(ushort* __restrict__ dst){
  int idx = blockIdx.x * blockDim.x + threadIdx.x;
  if (idx >= 640 * 512) return;
  int c = idx >> 9, n = idx & 511;
  float v = 0.f;
  if (c < 512) {
    int k = c >> 1, m = (k * n) & 511;
    float th = (float)m * (6.283185307179586f / 512.0f);
    float s, co; sincosf(th, &s, &co);
    float w = (k == 0) ? (1.0f / 512.0f) : (2.0f / 512.0f);
    v = (c & 1) ? -w * s : w * co;
  } else if (c == 512) {
    v = ((n & 1) ? -1.0f : 1.0f) / 512.0f;
  }
  split_pk(v, dst, 640, c, n);
}

// ================= elementwise =================
__global__ void convert_x_pk(const float* __restrict__ x, ushort* __restrict__ dst){
  int idx = blockIdx.x * blockDim.x + threadIdx.x;
  if (idx >= BN * 544) return;
  int r = idx / 544, c = idx - r * 544;
  float v = (c < 512) ? x[(size_t)r * 512 + c] : 0.f;
  split_pk(v, dst, BN, r, c);
}

// Nyquist: RI[n][512]=sum x*(-1)^i, RI[n][513]=0, mag bins 256..287
__global__ void nyq_kernel(const float* __restrict__ x, float* __restrict__ RI,
                           ushort* __restrict__ magpk){
  int row  = blockIdx.x * 4 + (threadIdx.x >> 6);
  int lane = threadIdx.x & 63;
  const float* xr = x + (size_t)row * 512;
  float s = 0.f;
  #pragma unroll
  for (int i = 0; i < 8; ++i) {
    int n = lane + 64 * i;
    float v = xr[n];
    s += (n & 1) ? -v : v;
  }
  #pragma unroll
  for (int off = 32; off >= 1; off >>= 1) s += __shfl_xor(s, off, 64);
  if (lane == 0) {
    RI[(size_t)row * 514 + 512] = s;
    RI[(size_t)row * 514 + 513] = 0.f;
  }
  if (lane < 32) {
    float mg = (lane == 0) ? sqrtf(fmaxf(s * s, EPSF)) : 0.f;
    split_pk(mg, magpk, BN, row, 256 + lane);
  }
}

// in_state (2,BN,NH,2) f32 -> packed h + C f32 (both layers)
__global__ void unpack_state(const float* __restrict__ st,
                             ushort* __restrict__ h1pk, float* __restrict__ c1,
                             ushort* __restrict__ h2pk, float* __restrict__ c2){
  int idx = blockIdx.x * blockDim.x + threadIdx.x;
  if (idx >= BN * NH) return;
  int row = idx >> 7, u = idx & 127;
  split_pk(st[(size_t)idx * 2], h1pk, BN, row, u);
  c1[idx] = st[(size_t)idx * 2 + 1];
  size_t off = (size_t)BN * NH * 2;
  split_pk(st[off + (size_t)idx * 2], h2pk, BN, row, u);
  c2[idx] = st[off + (size_t)idx * 2 + 1];
}

// LayerNorm over 256 -> packed ENCN
__global__ void ln_kernel(const float* __restrict__ ENC,
                          const float* __restrict__ gamma,
                          const float* __restrict__ beta,
                          ushort* __restrict__ opk){
  int row = blockIdx.x;
  int t = threadIdx.x;   // 64; thread handles cols 4t..4t+3
  const float* e = ENC + (size_t)row * NE;
  float v[4]; float s = 0.f;
  #pragma unroll
  for (int i = 0; i < 4; ++i) { v[i] = e[4 * t + i]; s += v[i]; }
  #pragma unroll
  for (int off = 32; off >= 1; off >>= 1) s += __shfl_xor(s, off, 64);
  float mean = s * (1.0f / NE);
  float d[4]; float ss = 0.f;
  #pragma unroll
  for (int i = 0; i < 4; ++i) { d[i] = v[i] - mean; ss += d[i] * d[i]; }
  #pragma unroll
  for (int off = 32; off >= 1; off >>= 1) ss += __shfl_xor(ss, off, 64);
  float inv = 1.0f / sqrtf(ss * (1.0f / NE) + LNEPS);
  #pragma unroll
  for (int i = 0; i < 4; ++i) {
    int col = 4 * t + i;
    float o = d[i] * inv * gamma[col] + beta[col];
    split_pk(o, opk, BN, row, col);
  }
}

// ================= launch =================
extern "C" void kernel_launch(void* const* d_in, const int* in_sizes, int n_in,
                              void* d_out, int out_size, void* d_ws, size_t ws_size,
                              hipStream_t stream)
{
  const float* x       = (const float*)d_in[0];
  const float* st1     = (const float*)d_in[1];
  const float* st2     = (const float*)d_in[2];
  const float* s1_wih1 = (const float*)d_in[3];
  const float* s1_whh1 = (const float*)d_in[4];
  const float* s1_bih1 = (const float*)d_in[5];
  const float* s1_bhh1 = (const float*)d_in[6];
  const float* s1_wih2 = (const float*)d_in[7];
  const float* s1_whh2 = (const float*)d_in[8];
  const float* s1_bih2 = (const float*)d_in[9];
  const float* s1_bhh2 = (const float*)d_in[10];
  const float* s1_dw   = (const float*)d_in[11];
  const float* s1_db   = (const float*)d_in[12];
  const float* enc_w   = (const float*)d_in[13];
  const float* ln_g    = (const float*)d_in[14];
  const float* ln_b    = (const float*)d_in[15];
  const float* s2_wih1 = (const float*)d_in[16];
  const float* s2_whh1 = (const float*)d_in[17];
  const float* s2_bih1 = (const float*)d_in[18];
  const float* s2_bhh1 = (const float*)d_in[19];
  const float* s2_wih2 = (const float*)d_in[20];
  const float* s2_whh2 = (const float*)d_in[21];
  const float* s2_bih2 = (const float*)d_in[22];
  const float* s2_bhh2 = (const float*)d_in[23];
  const float* s2_dw   = (const float*)d_in[24];
  const float* s2_db   = (const float*)d_in[25];
  const float* dec_w   = (const float*)d_in[26];

  float* out_dec = (float*)d_out;
  float* out_st1 = out_dec + (size_t)BN * NFFT;
  float* out_st2 = out_st1 + (size_t)2 * BN * NH * 2;

  // ---- workspace ----
  char* base = (char*)d_ws;
  size_t off = 0;
  auto alloc = [&](size_t bytes) -> void* {
    off = (off + 255) & ~(size_t)255;
    void* p = base + off;
    off += bytes;
    return p;
  };
  auto pkbytes = [](int rows, int nk) -> size_t {
    return (size_t)nk * rows * 64 * 2;
  };
  ushort* fwdTpk  = (ushort*)alloc(pkbytes(512, 16));
  ushort* invTtpk = (ushort*)alloc(pkbytes(640, 16));
  ushort* MEpk    = (ushort*)alloc(pkbytes(256, 20));
  ushort* XSpk    = (ushort*)alloc(pkbytes(BN, 17));
  float*  RI      = (float*) alloc((size_t)BN * 514 * 4);
  ushort* magpk   = (ushort*)alloc(pkbytes(BN, 9));
  float*  ENC     = (float*) alloc((size_t)BN * NE * 4);
  ushort* ENCNpk  = (ushort*)alloc(pkbytes(BN, 8));
  ushort* Dpk     = (ushort*)alloc(pkbytes(BN, 8));
  ushort* h1pk    = (ushort*)alloc(pkbytes(BN, 4));
  ushort* h2pk    = (ushort*)alloc(pkbytes(BN, 4));
  ushort* h1npk   = (ushort*)alloc(pkbytes(BN, 4));
  ushort* h2npk   = (ushort*)alloc(pkbytes(BN, 4));
  float*  C1      = (float*) alloc((size_t)BN * NH * 4);
  float*  C2      = (float*) alloc((size_t)BN * NH * 4);
  ushort* w11pk   = (ushort*)alloc(pkbytes(512, 9));
  ushort* wh1pk   = (ushort*)alloc(pkbytes(512, 4));
  ushort* w12pk   = (ushort*)alloc(pkbytes(512, 4));
  ushort* wh2pk   = (ushort*)alloc(pkbytes(512, 4));
  ushort* dw1pk   = (ushort*)alloc(pkbytes(384, 4));
  ushort* encwpk  = (ushort*)alloc(pkbytes(256, 16));
  ushort* w21pk   = (ushort*)alloc(pkbytes(512, 8));
  ushort* wh3pk   = (ushort*)alloc(pkbytes(512, 4));
  ushort* w22pk   = (ushort*)alloc(pkbytes(512, 4));
  ushort* wh4pk   = (ushort*)alloc(pkbytes(512, 4));
  ushort* dw2pk   = (ushort*)alloc(pkbytes(256, 4));
  ushort* decwpk  = (ushort*)alloc(pkbytes(512, 8));
  float* bg1 = (float*)alloc(512*4); float* bg2 = (float*)alloc(512*4);
  float* bm1 = (float*)alloc(384*4);
  float* bg3 = (float*)alloc(512*4); float* bg4 = (float*)alloc(512*4);
  float* bm2 = (float*)alloc(256*4);
  (void)ws_size; (void)in_sizes; (void)n_in; (void)out_size;

  const dim3 blk(256);
  auto ceilb = [](long n){ return (int)((n + 255) / 256); };

  // ---- prep ----
  fill_fwd_pk<<<ceilb((long)512*512), blk, 0, stream>>>(fwdTpk);
  fill_invTt_pk<<<ceilb((long)640*512), blk, 0, stream>>>(invTtpk);
  wconv_g_pk<<<ceilb((long)512*288), blk, 0, stream>>>(s1_wih1, 257, w11pk, 288);
  wconv_g_pk<<<ceilb((long)512*128), blk, 0, stream>>>(s1_whh1, 128, wh1pk, 128);
  wconv_g_pk<<<ceilb((long)512*128), blk, 0, stream>>>(s1_wih2, 128, w12pk, 128);
  wconv_g_pk<<<ceilb((long)512*128), blk, 0, stream>>>(s1_whh2, 128, wh2pk, 128);
  wconv_pk<<<ceilb((long)384*128), blk, 0, stream>>>(s1_dw,   257, 128, dw1pk, 384, 128);
  wconv_pk<<<ceilb((long)256*512), blk, 0, stream>>>(enc_w,   256, 512, encwpk, 256, 512);
  wconv_g_pk<<<ceilb((long)512*256), blk, 0, stream>>>(s2_wih1, 256, w21pk, 256);
  wconv_g_pk<<<ceilb((long)512*128), blk, 0, stream>>>(s2_whh1, 128, wh3pk, 128);
  wconv_g_pk<<<ceilb((long)512*128), blk, 0, stream>>>(s2_wih2, 128, w22pk, 128);
  wconv_g_pk<<<ceilb((long)512*128), blk, 0, stream>>>(s2_whh2, 128, wh4pk, 128);
  wconv_pk<<<ceilb((long)256*128), blk, 0, stream>>>(s2_dw,   256, 128, dw2pk, 256, 128);
  wconv_pk<<<ceilb((long)512*256), blk, 0, stream>>>(dec_w,   512, 256, decwpk, 512, 256);
  bias_g<<<2, blk, 0, stream>>>(s1_bih1, s1_bhh1, bg1);
  bias_g<<<2, blk, 0, stream>>>(s1_bih2, s1_bhh2, bg2);
  bias_pad<<<2, blk, 0, stream>>>(s1_db,   nullptr, 257, bm1, 384);
  bias_g<<<2, blk, 0, stream>>>(s2_bih1, s2_bhh1, bg3);
  bias_g<<<2, blk, 0, stream>>>(s2_bih2, s2_bhh2, bg4);
  bias_pad<<<1, blk, 0, stream>>>(s2_db,   nullptr, 256, bm2, 256);

  // ---- ME = enc_w x invT (256x640, K=512) -> packed (folds irfft into enc) ----
  mfma_gemm<M_PLANES><<<dim3(4,5), blk, 0, stream>>>(encwpk, 256, 16, invTtpk, 640,
      nullptr, 0, nullptr, 0,
      nullptr, nullptr, 256, nullptr, nullptr, nullptr, MEpk);

  convert_x_pk<<<ceilb((long)BN*544), blk, 0, stream>>>(x, XSpk);
  unpack_state<<<ceilb((long)BN*NH), blk, 0, stream>>>(st1, h1pk, C1, h2pk, C2);

  // ---- rfft (+fused magphase) + Nyquist ----
  mfma_gemm<M_RFFT><<<dim3(256,4), blk, 0, stream>>>(XSpk, BN, 16, fwdTpk, 512,
      nullptr, 0, nullptr, 0,
      nullptr, RI, 514, nullptr, nullptr, nullptr, magpk);
  nyq_kernel<<<BN/4, blk, 0, stream>>>(x, RI, magpk);

  // ---- sep block 1 (fused LSTM epilogues) ----
  mfma_gemm<M_LSTM><<<dim3(256,4), blk, 0, stream>>>(magpk, BN, 9, w11pk, 512,
      h1pk, 4, wh1pk, 512,
      bg1, nullptr, 0, C1, nullptr, out_st1, h1npk);
  mfma_gemm<M_LSTM><<<dim3(256,4), blk, 0, stream>>>(h1npk, BN, 4, w12pk, 512,
      h2pk, 4, wh2pk, 512,
      bg2, nullptr, 0, C2, nullptr, out_st1 + (size_t)BN*NH*2, h2npk);
  // ---- mask1 + fused est_build -> XS packed ----
  mfma_gemm<M_EST><<<dim3(256,3), blk, 0, stream>>>(h2npk, BN, 4, dw1pk, 384,
      nullptr, 0, nullptr, 0,
      bm1, nullptr, 0, RI, magpk, nullptr, XSpk);

  // ---- encoder (irfft folded via ME) + LN ----
  mfma_gemm<M_F32><<<dim3(256,2), blk, 0, stream>>>(XSpk, BN, 17, MEpk, 256,
      nullptr, 0, nullptr, 0,
      nullptr, ENC, 256, nullptr, nullptr, nullptr, nullptr);
  ln_kernel<<<BN, 64, 0, stream>>>(ENC, ln_g, ln_b, ENCNpk);

  // ---- sep block 2 ----
  unpack_state<<<ceilb((long)BN*NH), blk, 0, stream>>>(st2, h1pk, C1, h2pk, C2);
  mfma_gemm<M_LSTM><<<dim3(256,4), blk, 0, stream>>>(ENCNpk, BN, 8, w21pk, 512,
      h1pk, 4, wh3pk, 512,
      bg3, nullptr, 0, C1, nullptr, out_st2, h1npk);
  mfma_gemm<M_LSTM><<<dim3(256,4), blk, 0, stream>>>(h1npk, BN, 4, w22pk, 512,
      h2pk, 4, wh4pk, 512,
      bg4, nullptr, 0, C2, nullptr, out_st2 + (size_t)BN*NH*2, h2npk);
  // ---- mask2 + fused dec_in -> D packed ----
  mfma_gemm<M_DEC><<<dim3(256,2), blk, 0, stream>>>(h2npk, BN, 4, dw2pk, 256,
      nullptr, 0, nullptr, 0,
      bm2, nullptr, 0, ENC, nullptr, nullptr, Dpk);

  // ---- decoder ----
  mfma_gemm<M_F32><<<dim3(256,4), blk, 0, stream>>>(Dpk, BN, 8, decwpk, 512,
      nullptr, 0, nullptr, 0,
      nullptr, out_dec, 512, nullptr, nullptr, nullptr, nullptr);
}